// Round 7
// baseline (279.090 us; speedup 1.0000x reference)
//
#include <hip/hip_runtime.h>

#define B_SZ 8
#define N1 8192
#define N2 2048
#define C1 128
#define C2 256
#define CIN 384
#define M0 256
#define NP (B_SZ * N1)   // 65536
#define CHUNKS 8
#define CHUNK (N2 / CHUNKS)   // 256
#define ASTRIDE 392          // gemm1 A-tile LDS row stride (384+8 bf16)
#define A2STRIDE 264         // gemm2 A-tile LDS row stride (256+8 bf16)

typedef __bf16 bf16_t;
typedef bf16_t bf16x8 __attribute__((ext_vector_type(8)));
typedef bf16_t bf16x4 __attribute__((ext_vector_type(4)));
typedef float  f32x4  __attribute__((ext_vector_type(4)));

// ---------------- fp32 -> bf16 converts ----------------
__global__ void cvt_bf16_kernel(const float* __restrict__ in, bf16_t* __restrict__ out, int n) {
    int i = blockIdx.x * 256 + threadIdx.x;
    if (i < n) out[i] = (bf16_t)in[i];
}
__global__ void cvt_bf16x4_kernel(const float* __restrict__ in, bf16_t* __restrict__ out) {
    int tid = blockIdx.x * 256 + threadIdx.x;
    float4 v = ((const float4*)in)[tid];
    bf16x4 o;
    o[0] = (bf16_t)v.x; o[1] = (bf16_t)v.y; o[2] = (bf16_t)v.z; o[3] = (bf16_t)v.w;
    ((bf16x4*)out)[tid] = o;
}

// ---------------- prep: xyz2 -> float4 (x,y,z,|q|^2) for uniform-path reads ----------------
__global__ void prep_x2n_kernel(const float* __restrict__ xyz2, float4* __restrict__ x2n) {
    int t = blockIdx.x * 256 + threadIdx.x;   // over B_SZ*N2 = 16384
    float x = xyz2[t * 3 + 0], y = xyz2[t * 3 + 1], z = xyz2[t * 3 + 2];
    x2n[t] = make_float4(x, y, z, x * x + y * y + z * z);
}

// ---------------- 3-NN partial: candidates via uniform-address loads, no LDS ----------------
// Diagnosis across R0-R3: the per-candidate ds_read_b128 broadcast kept the per-CU DS
// pipe ~65% busy (8192 b128/CU) and every wave queued on lgkmcnt behind 31 others.
// Candidates are wave-uniform -> read precomputed float4 (x,y,z,norm) through a
// uniform-indexed const __restrict__ pointer (base derives only from blockIdx, already
// SGPR-resident): compiler emits s_load (SMEM pipe) or uniform global_load (L1
// broadcast) -- either way the DS pipe is freed. Distance in strict
// 1-SGPR-per-inst association (mul,fma,fma,add). Insert is the original R0 ternary
// form; |p|^2 deferred out of the loop (compare-invariant, added back at store).
// Selection semantics identical to baseline.
__global__ __launch_bounds__(256) void nn3_partial_kernel(const float* __restrict__ xyz1,
                                                          const float4* __restrict__ x2n,
                                                          float* __restrict__ pd,
                                                          int* __restrict__ pi) {
    int b = blockIdx.x >> 5;
    int i = ((blockIdx.x & 31) << 8) + threadIdx.x;
    int c = blockIdx.y;
    const float4* __restrict__ xc = x2n + (b * N2 + c * CHUNK);
    const float* p = xyz1 + ((size_t)b * N1 + i) * 3;
    float px = p[0], py = p[1], pz = p[2];
    float pn = px * px + py * py + pz * pz;
    float px2 = -2.0f * px, py2 = -2.0f * py, pz2 = -2.0f * pz;
    float d0 = 1e30f, d1 = 1e30f, d2 = 1e30f;
    int   j0 = 0,     j1 = 0,     j2 = 0;
#pragma unroll 8
    for (int j = 0; j < CHUNK; ++j) {
        float4 v = xc[j];
        float t0 = px2 * v.x;                 // 1 SGPR operand per VALU inst
        float t1 = fmaf(py2, v.y, t0);
        float t2 = fmaf(pz2, v.z, t1);
        float sq = t2 + v.w;
        bool c0 = sq < d0, c1 = sq < d1, c2 = sq < d2;
        d2 = c1 ? d1 : (c2 ? sq : d2);
        j2 = c1 ? j1 : (c2 ? j  : j2);
        d1 = c0 ? d0 : (c1 ? sq : d1);
        j1 = c0 ? j0 : (c1 ? j  : j1);
        d0 = c0 ? sq : d0;
        j0 = c0 ? j  : j0;
    }
    int jb = c * CHUNK;
    size_t pidx = (size_t)b * N1 + i;
    pd[((size_t)c * 3 + 0) * NP + pidx] = d0 + pn;
    pd[((size_t)c * 3 + 1) * NP + pidx] = d1 + pn;
    pd[((size_t)c * 3 + 2) * NP + pidx] = d2 + pn;
    pi[((size_t)c * 3 + 0) * NP + pidx] = j0 + jb;
    pi[((size_t)c * 3 + 1) * NP + pidx] = j1 + jb;
    pi[((size_t)c * 3 + 2) * NP + pidx] = j2 + jb;
}

// ---------------- merge partials, sqrt + weights ----------------
__global__ void nn3_merge_kernel(const float* __restrict__ pd, const int* __restrict__ pi,
                                 int* __restrict__ idx3, float* __restrict__ w3) {
    int p = blockIdx.x * 256 + threadIdx.x;
    float d0 = 1e30f, d1 = 1e30f, d2 = 1e30f;
    int   j0 = 0,     j1 = 0,     j2 = 0;
#pragma unroll
    for (int k = 0; k < CHUNKS * 3; ++k) {
        float d = pd[(size_t)k * NP + p];
        int   j = pi[(size_t)k * NP + p];
        bool c0 = d < d0, c1 = d < d1, c2 = d < d2;
        d2 = c1 ? d1 : (c2 ? d : d2);
        j2 = c1 ? j1 : (c2 ? j : j2);
        d1 = c0 ? d0 : (c1 ? d : d1);
        j1 = c0 ? j0 : (c1 ? j : j1);
        d0 = c0 ? d : d0;
        j0 = c0 ? j : j0;
    }
    float r0 = sqrtf(fmaxf(d0, 0.0f));
    float r1 = sqrtf(fmaxf(d1, 0.0f));
    float r2 = sqrtf(fmaxf(d2, 0.0f));
    float inv0 = 1.0f / (r0 + 1e-8f);
    float inv1 = 1.0f / (r1 + 1e-8f);
    float inv2 = 1.0f / (r2 + 1e-8f);
    float s = inv0 + inv1 + inv2;
    size_t o = (size_t)p * 3;
    w3[o] = inv0 / s; w3[o + 1] = inv1 / s; w3[o + 2] = inv2 / s;
    idx3[o] = j0; idx3[o + 1] = j1; idx3[o + 2] = j2;
}

// ---------------- GEMM1 fused gather: bf16 points2, staged idx/w, 8 col-waves (W read 1x) ----
// grid NP/64 = 1024 blocks; batch->XCD swizzle (batch = blk&7).
__global__ __launch_bounds__(512) void gemm1_fused_kernel(const float* __restrict__ points1,
                                                          const bf16_t* __restrict__ P2b,
                                                          const int* __restrict__ idx3,
                                                          const float* __restrict__ w3,
                                                          const bf16_t* __restrict__ Wt,
                                                          bf16_t* __restrict__ H,
                                                          float* __restrict__ P0) {
    __shared__ bf16_t As[64 * ASTRIDE];   // 50176 B
    __shared__ int   si[192];             // 768 B
    __shared__ float sw[192];             // 768 B -> 51712 B total: 3 blocks/CU
    int bb   = blockIdx.x & 7;
    int tile = blockIdx.x >> 3;
    int row0 = bb * N1 + tile * 64;
    // stage idx/w coalesced
    if (threadIdx.x < 192)
        si[threadIdx.x] = idx3[(size_t)row0 * 3 + threadIdx.x];
    else if (threadIdx.x >= 256 && threadIdx.x < 448)
        sw[threadIdx.x - 256] = w3[(size_t)row0 * 3 + (threadIdx.x - 256)];
    __syncthreads();
    // ---- phase 1: interp (bf16 rows) + points1 copy into LDS; 8 threads/point ----
    {
        int pt  = threadIdx.x >> 3;
        int sub = threadIdx.x & 7;
        int i0 = si[pt * 3], i1 = si[pt * 3 + 1], i2 = si[pt * 3 + 2];
        float w0 = sw[pt * 3], w1 = sw[pt * 3 + 1], w2 = sw[pt * 3 + 2];
        const bf16_t* P2 = P2b + (size_t)bb * N2 * C2;
        const bf16_t* r0 = P2 + (size_t)i0 * C2;
        const bf16_t* r1 = P2 + (size_t)i1 * C2;
        const bf16_t* r2 = P2 + (size_t)i2 * C2;
        bf16_t* Ar = As + pt * ASTRIDE;
#pragma unroll
        for (int q = 0; q < 4; ++q) {
            int c = q * 64 + sub * 8;
            bf16x8 va = *(const bf16x8*)(r0 + c);
            bf16x8 vb = *(const bf16x8*)(r1 + c);
            bf16x8 vc = *(const bf16x8*)(r2 + c);
            bf16x8 o;
#pragma unroll
            for (int j = 0; j < 8; ++j)
                o[j] = (bf16_t)(w0 * (float)va[j] + w1 * (float)vb[j] + w2 * (float)vc[j]);
            *(bf16x8*)(Ar + c) = o;
        }
        const float* p1 = points1 + (size_t)(row0 + pt) * C1;
#pragma unroll
        for (int q = 0; q < 4; ++q) {
            int c = q * 32 + sub * 4;
            float4 v = *(const float4*)(p1 + c);
            bf16x4 o;
            o[0] = (bf16_t)v.x; o[1] = (bf16_t)v.y; o[2] = (bf16_t)v.z; o[3] = (bf16_t)v.w;
            *(bf16x4*)(Ar + C2 + c) = o;
        }
    }
    __syncthreads();
    // ---- phase 2: wave w -> cols [w*32, w*32+32), all 64 rows. W slice private to wave. ----
    int w    = threadIdx.x >> 6;
    int lane = threadIdx.x & 63;
    int l15  = lane & 15;
    int quad = lane >> 4;
    f32x4 acc[4][2] = {};
    const bf16_t* Wp = Wt + ((size_t)(w * 32) + l15) * CIN + quad * 8;
    const bf16_t* Al = As + l15 * ASTRIDE + quad * 8;
    for (int k0 = 0; k0 < CIN; k0 += 32) {
        bf16x8 bfr[2];
#pragma unroll
        for (int ni = 0; ni < 2; ++ni) bfr[ni] = *(const bf16x8*)(Wp + (size_t)ni * 16 * CIN + k0);
#pragma unroll
        for (int mi = 0; mi < 4; ++mi) {
            bf16x8 a = *(const bf16x8*)(Al + mi * 16 * ASTRIDE + k0);
            acc[mi][0] = __builtin_amdgcn_mfma_f32_16x16x32_bf16(a, bfr[0], acc[mi][0], 0, 0, 0);
            acc[mi][1] = __builtin_amdgcn_mfma_f32_16x16x32_bf16(a, bfr[1], acc[mi][1], 0, 0, 0);
        }
    }
    // ---- epilogue: H store + per-block column stats (each column owned by one lane) ----
#pragma unroll
    for (int mi = 0; mi < 4; ++mi)
#pragma unroll
        for (int ni = 0; ni < 2; ++ni) {
            int col  = w * 32 + ni * 16 + l15;
            int rowb = row0 + mi * 16 + quad * 4;
#pragma unroll
            for (int r = 0; r < 4; ++r)
                H[(size_t)(rowb + r) * 256 + col] = (bf16_t)acc[mi][ni][r];
        }
#pragma unroll
    for (int ni = 0; ni < 2; ++ni) {
        float s = 0.0f, ss = 0.0f;
#pragma unroll
        for (int mi = 0; mi < 4; ++mi)
#pragma unroll
            for (int r = 0; r < 4; ++r) {
                float v = acc[mi][ni][r];
                s += v; ss = fmaf(v, v, ss);
            }
        s  += __shfl_xor(s, 16);  s  += __shfl_xor(s, 32);
        ss += __shfl_xor(ss, 16); ss += __shfl_xor(ss, 32);
        if (quad == 0) {
            int cl = w * 32 + ni * 16 + l15;      // unique per lane across block
            float* slot = P0 + (size_t)blockIdx.x * 512;
            slot[cl]       = s;
            slot[256 + cl] = ss;
        }
    }
}

// ---------------- GEMM2: A staged in LDS with fused BN+ReLU (1x), 8 col-waves (W 1x) ----------
// grid NP/64 = 1024 blocks.
__global__ __launch_bounds__(512) void gemm2_kernel(const bf16_t* __restrict__ A,
                                                    const bf16_t* __restrict__ Wt,
                                                    const float* __restrict__ scale,
                                                    const float* __restrict__ shift,
                                                    bf16_t* __restrict__ H,
                                                    float* __restrict__ P1) {
    const int K = M0;   // 256
    __shared__ bf16_t As2[64 * A2STRIDE];   // 33792 B
    __shared__ float ssc[256], ssh[256];    // 2 KB
    int row0 = blockIdx.x * 64;
    if (threadIdx.x < 256) { ssc[threadIdx.x] = scale[threadIdx.x]; ssh[threadIdx.x] = shift[threadIdx.x]; }
    __syncthreads();
    // stage A-tile: 64 rows x 256 ch, BN+ReLU applied once; coalesced 16B loads
#pragma unroll
    for (int rI = 0; rI < 4; ++rI) {
        int idx = rI * 512 + threadIdx.x;     // 0..2047
        int row = idx >> 5;
        int c8  = (idx & 31) * 8;
        bf16x8 raw = *(const bf16x8*)(A + (size_t)(row0 + row) * 256 + c8);
        bf16x8 t;
#pragma unroll
        for (int j = 0; j < 8; ++j)
            t[j] = (bf16_t)fmaxf(fmaf((float)raw[j], ssc[c8 + j], ssh[c8 + j]), 0.0f);
        *(bf16x8*)(As2 + row * A2STRIDE + c8) = t;
    }
    __syncthreads();
    int w    = threadIdx.x >> 6;
    int lane = threadIdx.x & 63;
    int l15  = lane & 15;
    int quad = lane >> 4;
    f32x4 acc[4][2] = {};
    const bf16_t* Wp = Wt + ((size_t)(w * 32) + l15) * K + quad * 8;
    const bf16_t* Al = As2 + l15 * A2STRIDE + quad * 8;
    for (int k0 = 0; k0 < K; k0 += 32) {
        bf16x8 bfr[2];
#pragma unroll
        for (int ni = 0; ni < 2; ++ni) bfr[ni] = *(const bf16x8*)(Wp + (size_t)ni * 16 * K + k0);
#pragma unroll
        for (int mi = 0; mi < 4; ++mi) {
            bf16x8 a = *(const bf16x8*)(Al + mi * 16 * A2STRIDE + k0);
            acc[mi][0] = __builtin_amdgcn_mfma_f32_16x16x32_bf16(a, bfr[0], acc[mi][0], 0, 0, 0);
            acc[mi][1] = __builtin_amdgcn_mfma_f32_16x16x32_bf16(a, bfr[1], acc[mi][1], 0, 0, 0);
        }
    }
#pragma unroll
    for (int mi = 0; mi < 4; ++mi)
#pragma unroll
        for (int ni = 0; ni < 2; ++ni) {
            int col  = w * 32 + ni * 16 + l15;
            int rowb = row0 + mi * 16 + quad * 4;
#pragma unroll
            for (int r = 0; r < 4; ++r)
                H[(size_t)(rowb + r) * 256 + col] = (bf16_t)acc[mi][ni][r];
        }
#pragma unroll
    for (int ni = 0; ni < 2; ++ni) {
        float s = 0.0f, ss = 0.0f;
#pragma unroll
        for (int mi = 0; mi < 4; ++mi)
#pragma unroll
            for (int r = 0; r < 4; ++r) {
                float v = acc[mi][ni][r];
                s += v; ss = fmaf(v, v, ss);
            }
        s  += __shfl_xor(s, 16);  s  += __shfl_xor(s, 32);
        ss += __shfl_xor(ss, 16); ss += __shfl_xor(ss, 32);
        if (quad == 0) {
            int cl = w * 32 + ni * 16 + l15;
            float* slot = P1 + (size_t)blockIdx.x * 512;
            slot[cl]       = s;
            slot[256 + cl] = ss;
        }
    }
}

// ---------------- reduce per-block partials -> scale/shift (one block per channel) ----------------
__global__ __launch_bounds__(256) void finalize_partials_kernel(const float* __restrict__ P, int nblk,
                                                                const float* __restrict__ gamma,
                                                                const float* __restrict__ beta,
                                                                float* __restrict__ scale,
                                                                float* __restrict__ shift) {
    int c = blockIdx.x;
    float s = 0.0f, ss = 0.0f;
    for (int bb = threadIdx.x; bb < nblk; bb += 256) {
        const float* row = P + (size_t)bb * 512;
        s  += row[c];
        ss += row[256 + c];
    }
#pragma unroll
    for (int k = 32; k >= 1; k >>= 1) { s += __shfl_xor(s, k); ss += __shfl_xor(ss, k); }
    __shared__ float as_[4], ass_[4];
    int w = threadIdx.x >> 6;
    if ((threadIdx.x & 63) == 0) { as_[w] = s; ass_[w] = ss; }
    __syncthreads();
    if (threadIdx.x == 0) {
        float S  = as_[0] + as_[1] + as_[2] + as_[3];
        float SS = ass_[0] + ass_[1] + ass_[2] + ass_[3];
        float m   = S * (1.0f / NP);
        float var = SS * (1.0f / NP) - m * m;
        float sc  = rsqrtf(var + 1e-5f) * gamma[c];
        scale[c] = sc;
        shift[c] = fmaf(-m, sc, beta[c]);
    }
}

// ---------------- final BN+ReLU: H1 bf16 -> fp32 d_out ----------------
__global__ void bnrelu_final_kernel(const bf16_t* __restrict__ H, const float* __restrict__ scale,
                                    const float* __restrict__ shift, float* __restrict__ out) {
    int tid = blockIdx.x * 256 + threadIdx.x;
    bf16x8 v = *(const bf16x8*)(H + (size_t)tid * 8);
    int c = (tid & 31) * 8;
    float4 o0, o1;
    o0.x = fmaxf(fmaf((float)v[0], scale[c + 0], shift[c + 0]), 0.0f);
    o0.y = fmaxf(fmaf((float)v[1], scale[c + 1], shift[c + 1]), 0.0f);
    o0.z = fmaxf(fmaf((float)v[2], scale[c + 2], shift[c + 2]), 0.0f);
    o0.w = fmaxf(fmaf((float)v[3], scale[c + 3], shift[c + 3]), 0.0f);
    o1.x = fmaxf(fmaf((float)v[4], scale[c + 4], shift[c + 4]), 0.0f);
    o1.y = fmaxf(fmaf((float)v[5], scale[c + 5], shift[c + 5]), 0.0f);
    o1.z = fmaxf(fmaf((float)v[6], scale[c + 6], shift[c + 6]), 0.0f);
    o1.w = fmaxf(fmaf((float)v[7], scale[c + 7], shift[c + 7]), 0.0f);
    ((float4*)out)[tid * 2]     = o0;
    ((float4*)out)[tid * 2 + 1] = o1;
}

extern "C" void kernel_launch(void* const* d_in, const int* in_sizes, int n_in,
                              void* d_out, int out_size, void* d_ws, size_t ws_size,
                              hipStream_t stream) {
    const float* xyz1    = (const float*)d_in[0];
    const float* xyz2    = (const float*)d_in[1];
    const float* points1 = (const float*)d_in[2];
    const float* points2 = (const float*)d_in[3];
    const float* W0      = (const float*)d_in[4];
    const float* g0      = (const float*)d_in[5];
    const float* b0      = (const float*)d_in[6];
    const float* W1      = (const float*)d_in[7];
    const float* g1      = (const float*)d_in[8];
    const float* b1      = (const float*)d_in[9];
    float* out = (float*)d_out;

    // ws layout (float offsets), ~85.8 MB
    float* wsf    = (float*)d_ws;
    float* scale0 = wsf + 0;
    float* shift0 = wsf + 256;
    float* scale1 = wsf + 512;
    float* shift1 = wsf + 768;
    float* w3     = wsf + 2048;                       // 196608 f
    int*   idx3   = (int*)(wsf + 198656);             // 196608 i
    bf16_t* Wb0   = (bf16_t*)(wsf + 395264);          // 98304 bf16
    bf16_t* Wb1   = (bf16_t*)(wsf + 444416);          // 65536 bf16
    float* pd     = wsf + 477184;                     // NP*24 f (dead after merge)
    int*   pi     = (int*)(wsf + 2050048);            // NP*24 i
    bf16_t* P2b   = (bf16_t*)(wsf + 477184);          // 4194304 bf16, aliases pd (cvt after merge)
    bf16_t* H0    = (bf16_t*)(wsf + 3622912);         // NP*256 bf16
    float4* x2n   = (float4*)(wsf + 3622912);         // 16384 float4, aliases H0 (dead before gemm1)
    bf16_t* H1    = (bf16_t*)(wsf + 12011520);        // NP*256 bf16
    float* P0     = wsf + 20400128;                   // 1024*512 f
    float* P1     = wsf + 20924416;                   // 1024*512 f -> ends 21448704 f

    cvt_bf16_kernel<<<(M0 * CIN + 255) / 256, 256, 0, stream>>>(W0, Wb0, M0 * CIN);
    cvt_bf16_kernel<<<(M0 * M0 + 255) / 256, 256, 0, stream>>>(W1, Wb1, M0 * M0);

    prep_x2n_kernel<<<(B_SZ * N2) / 256, 256, 0, stream>>>(xyz2, x2n);
    nn3_partial_kernel<<<dim3(B_SZ * (N1 / 256), CHUNKS), 256, 0, stream>>>(xyz1, x2n, pd, pi);
    nn3_merge_kernel<<<NP / 256, 256, 0, stream>>>(pd, pi, idx3, w3);

    // points2 -> bf16 (into the dead pd/pi region)
    cvt_bf16x4_kernel<<<(B_SZ * N2 * C2 / 4) / 256, 256, 0, stream>>>(points2, P2b);

    // layer 0
    gemm1_fused_kernel<<<NP / 64, 512, 0, stream>>>(points1, P2b, idx3, w3, Wb0, H0, P0);
    finalize_partials_kernel<<<256, 256, 0, stream>>>(P0, NP / 64, g0, b0, scale0, shift0);

    // layer 1
    gemm2_kernel<<<NP / 64, 512, 0, stream>>>(H0, Wb1, scale0, shift0, H1, P1);
    finalize_partials_kernel<<<256, 256, 0, stream>>>(P1, NP / 64, g1, b1, scale1, shift1);

    // final BN+ReLU -> fp32 output
    bnrelu_final_kernel<<<NP * 256 / 8 / 256, 256, 0, stream>>>(H1, scale1, shift1, out);
}

// Round 8
// 272.793 us; speedup vs baseline: 1.0231x; 1.0231x over previous
//
#include <hip/hip_runtime.h>

#define B_SZ 8
#define N1 8192
#define N2 2048
#define C1 128
#define C2 256
#define CIN 384
#define M0 256
#define NP (B_SZ * N1)   // 65536
#define CHUNKS 16
#define CHUNK (N2 / CHUNKS)   // 128
#define ASTRIDE 392          // gemm1 A-tile LDS row stride (384+8 bf16)
#define A2STRIDE 264         // gemm2 A-tile LDS row stride (256+8 bf16)

typedef __bf16 bf16_t;
typedef bf16_t bf16x8 __attribute__((ext_vector_type(8)));
typedef bf16_t bf16x4 __attribute__((ext_vector_type(4)));
typedef float  f32x4  __attribute__((ext_vector_type(4)));

// ---------------- fp32 -> bf16 converts ----------------
__global__ void cvt_bf16_kernel(const float* __restrict__ in, bf16_t* __restrict__ out, int n) {
    int i = blockIdx.x * 256 + threadIdx.x;
    if (i < n) out[i] = (bf16_t)in[i];
}
__global__ void cvt_bf16x4_kernel(const float* __restrict__ in, bf16_t* __restrict__ out) {
    int tid = blockIdx.x * 256 + threadIdx.x;
    float4 v = ((const float4*)in)[tid];
    bf16x4 o;
    o[0] = (bf16_t)v.x; o[1] = (bf16_t)v.y; o[2] = (bf16_t)v.z; o[3] = (bf16_t)v.w;
    ((bf16x4*)out)[tid] = o;
}

// ---------------- 3-NN partial: MQ=2 at FULL occupancy ----------------
// R0-R6 scoreboard: LDS/ternary 62.2 | med3 64.6 | dual-chain 76.6 | MQ2@halfocc 70.0
// | scalar-path 74.6. Model: DS-pipe ~98k cy/CU and VALU ~70k cy/SIMD interact; R3
// proved DS amortization works but paid 2x occupancy. Fix: halve CHUNK to 128 and
// double CHUNKS to 16 -> grid stays 2048 blocks x 4 waves (32 waves/CU, R0-level
// occupancy) while each ds_read feeds TWO queries (i0, i0+256). DS/CU halves to
// ~49k cy; VALU becomes the binding pipe. Insert = R0 ternary form (empirically
// best); |p|^2 deferred (compare-invariant, added at store). Selection semantics
// exact: ascending-j strict-< within chunk, chunks merged ascending.
__global__ __launch_bounds__(256) void nn3_partial_kernel(const float* __restrict__ xyz1,
                                                          const float* __restrict__ xyz2,
                                                          float* __restrict__ pd,
                                                          int* __restrict__ pi) {
    __shared__ float4 s2[CHUNK];   // 2 KB
    int b  = blockIdx.x >> 4;                             // 16 blocks/batch (8192/512)
    int i0 = ((blockIdx.x & 15) << 9) + threadIdx.x;      // queries i0 and i0+256
    int c  = blockIdx.y;
    const float* x2 = xyz2 + ((size_t)b * N2 + (size_t)c * CHUNK) * 3;
    if (threadIdx.x < CHUNK) {
        int j = threadIdx.x;
        float x = x2[j * 3 + 0], y = x2[j * 3 + 1], z = x2[j * 3 + 2];
        s2[j] = make_float4(x, y, z, x * x + y * y + z * z);
    }
    __syncthreads();
    const float* pA = xyz1 + ((size_t)b * N1 + i0) * 3;
    const float* pB = pA + 256 * 3;
    float axq = pA[0], ayq = pA[1], azq = pA[2];
    float bxq = pB[0], byq = pB[1], bzq = pB[2];
    float apn = axq * axq + ayq * ayq + azq * azq;
    float bpn = bxq * bxq + byq * byq + bzq * bzq;
    float ax2 = -2.0f * axq, ay2 = -2.0f * ayq, az2 = -2.0f * azq;
    float bx2 = -2.0f * bxq, by2 = -2.0f * byq, bz2 = -2.0f * bzq;
    float Ad0 = 1e30f, Ad1 = 1e30f, Ad2 = 1e30f;
    int   Aj0 = 0,     Aj1 = 0,     Aj2 = 0;
    float Bd0 = 1e30f, Bd1 = 1e30f, Bd2 = 1e30f;
    int   Bj0 = 0,     Bj1 = 0,     Bj2 = 0;
#pragma unroll 4
    for (int j = 0; j < CHUNK; ++j) {
        float4 v = s2[j];
        float da = fmaf(ax2, v.x, fmaf(ay2, v.y, fmaf(az2, v.z, v.w)));
        float db = fmaf(bx2, v.x, fmaf(by2, v.y, fmaf(bz2, v.z, v.w)));
        {
            bool c0 = da < Ad0, c1 = da < Ad1, c2 = da < Ad2;
            Ad2 = c1 ? Ad1 : (c2 ? da : Ad2);
            Aj2 = c1 ? Aj1 : (c2 ? j  : Aj2);
            Ad1 = c0 ? Ad0 : (c1 ? da : Ad1);
            Aj1 = c0 ? Aj0 : (c1 ? j  : Aj1);
            Ad0 = c0 ? da : Ad0;
            Aj0 = c0 ? j  : Aj0;
        }
        {
            bool c0 = db < Bd0, c1 = db < Bd1, c2 = db < Bd2;
            Bd2 = c1 ? Bd1 : (c2 ? db : Bd2);
            Bj2 = c1 ? Bj1 : (c2 ? j  : Bj2);
            Bd1 = c0 ? Bd0 : (c1 ? db : Bd1);
            Bj1 = c0 ? Bj0 : (c1 ? j  : Bj1);
            Bd0 = c0 ? db : Bd0;
            Bj0 = c0 ? j  : Bj0;
        }
    }
    int jb = c * CHUNK;
    size_t pidx0 = (size_t)b * N1 + i0;
    size_t pidx1 = pidx0 + 256;
    pd[((size_t)c * 3 + 0) * NP + pidx0] = Ad0 + apn;
    pd[((size_t)c * 3 + 1) * NP + pidx0] = Ad1 + apn;
    pd[((size_t)c * 3 + 2) * NP + pidx0] = Ad2 + apn;
    pi[((size_t)c * 3 + 0) * NP + pidx0] = Aj0 + jb;
    pi[((size_t)c * 3 + 1) * NP + pidx0] = Aj1 + jb;
    pi[((size_t)c * 3 + 2) * NP + pidx0] = Aj2 + jb;
    pd[((size_t)c * 3 + 0) * NP + pidx1] = Bd0 + bpn;
    pd[((size_t)c * 3 + 1) * NP + pidx1] = Bd1 + bpn;
    pd[((size_t)c * 3 + 2) * NP + pidx1] = Bd2 + bpn;
    pi[((size_t)c * 3 + 0) * NP + pidx1] = Bj0 + jb;
    pi[((size_t)c * 3 + 1) * NP + pidx1] = Bj1 + jb;
    pi[((size_t)c * 3 + 2) * NP + pidx1] = Bj2 + jb;
}

// ---------------- merge partials, sqrt + weights ----------------
__global__ void nn3_merge_kernel(const float* __restrict__ pd, const int* __restrict__ pi,
                                 int* __restrict__ idx3, float* __restrict__ w3) {
    int p = blockIdx.x * 256 + threadIdx.x;
    float d0 = 1e30f, d1 = 1e30f, d2 = 1e30f;
    int   j0 = 0,     j1 = 0,     j2 = 0;
#pragma unroll 8
    for (int k = 0; k < CHUNKS * 3; ++k) {
        float d = pd[(size_t)k * NP + p];
        int   j = pi[(size_t)k * NP + p];
        bool c0 = d < d0, c1 = d < d1, c2 = d < d2;
        d2 = c1 ? d1 : (c2 ? d : d2);
        j2 = c1 ? j1 : (c2 ? j : j2);
        d1 = c0 ? d0 : (c1 ? d : d1);
        j1 = c0 ? j0 : (c1 ? j : j1);
        d0 = c0 ? d : d0;
        j0 = c0 ? j : j0;
    }
    float r0 = sqrtf(fmaxf(d0, 0.0f));
    float r1 = sqrtf(fmaxf(d1, 0.0f));
    float r2 = sqrtf(fmaxf(d2, 0.0f));
    float inv0 = 1.0f / (r0 + 1e-8f);
    float inv1 = 1.0f / (r1 + 1e-8f);
    float inv2 = 1.0f / (r2 + 1e-8f);
    float s = inv0 + inv1 + inv2;
    size_t o = (size_t)p * 3;
    w3[o] = inv0 / s; w3[o + 1] = inv1 / s; w3[o + 2] = inv2 / s;
    idx3[o] = j0; idx3[o + 1] = j1; idx3[o + 2] = j2;
}

// ---------------- GEMM1 fused gather: bf16 points2, staged idx/w, 8 col-waves (W read 1x) ----
// grid NP/64 = 1024 blocks; batch->XCD swizzle (batch = blk&7).
__global__ __launch_bounds__(512) void gemm1_fused_kernel(const float* __restrict__ points1,
                                                          const bf16_t* __restrict__ P2b,
                                                          const int* __restrict__ idx3,
                                                          const float* __restrict__ w3,
                                                          const bf16_t* __restrict__ Wt,
                                                          bf16_t* __restrict__ H,
                                                          float* __restrict__ P0) {
    __shared__ bf16_t As[64 * ASTRIDE];   // 50176 B
    __shared__ int   si[192];             // 768 B
    __shared__ float sw[192];             // 768 B -> 51712 B total: 3 blocks/CU
    int bb   = blockIdx.x & 7;
    int tile = blockIdx.x >> 3;
    int row0 = bb * N1 + tile * 64;
    // stage idx/w coalesced
    if (threadIdx.x < 192)
        si[threadIdx.x] = idx3[(size_t)row0 * 3 + threadIdx.x];
    else if (threadIdx.x >= 256 && threadIdx.x < 448)
        sw[threadIdx.x - 256] = w3[(size_t)row0 * 3 + (threadIdx.x - 256)];
    __syncthreads();
    // ---- phase 1: interp (bf16 rows) + points1 copy into LDS; 8 threads/point ----
    {
        int pt  = threadIdx.x >> 3;
        int sub = threadIdx.x & 7;
        int i0 = si[pt * 3], i1 = si[pt * 3 + 1], i2 = si[pt * 3 + 2];
        float w0 = sw[pt * 3], w1 = sw[pt * 3 + 1], w2 = sw[pt * 3 + 2];
        const bf16_t* P2 = P2b + (size_t)bb * N2 * C2;
        const bf16_t* r0 = P2 + (size_t)i0 * C2;
        const bf16_t* r1 = P2 + (size_t)i1 * C2;
        const bf16_t* r2 = P2 + (size_t)i2 * C2;
        bf16_t* Ar = As + pt * ASTRIDE;
#pragma unroll
        for (int q = 0; q < 4; ++q) {
            int c = q * 64 + sub * 8;
            bf16x8 va = *(const bf16x8*)(r0 + c);
            bf16x8 vb = *(const bf16x8*)(r1 + c);
            bf16x8 vc = *(const bf16x8*)(r2 + c);
            bf16x8 o;
#pragma unroll
            for (int j = 0; j < 8; ++j)
                o[j] = (bf16_t)(w0 * (float)va[j] + w1 * (float)vb[j] + w2 * (float)vc[j]);
            *(bf16x8*)(Ar + c) = o;
        }
        const float* p1 = points1 + (size_t)(row0 + pt) * C1;
#pragma unroll
        for (int q = 0; q < 4; ++q) {
            int c = q * 32 + sub * 4;
            float4 v = *(const float4*)(p1 + c);
            bf16x4 o;
            o[0] = (bf16_t)v.x; o[1] = (bf16_t)v.y; o[2] = (bf16_t)v.z; o[3] = (bf16_t)v.w;
            *(bf16x4*)(Ar + C2 + c) = o;
        }
    }
    __syncthreads();
    // ---- phase 2: wave w -> cols [w*32, w*32+32), all 64 rows. W slice private to wave. ----
    int w    = threadIdx.x >> 6;
    int lane = threadIdx.x & 63;
    int l15  = lane & 15;
    int quad = lane >> 4;
    f32x4 acc[4][2] = {};
    const bf16_t* Wp = Wt + ((size_t)(w * 32) + l15) * CIN + quad * 8;
    const bf16_t* Al = As + l15 * ASTRIDE + quad * 8;
    for (int k0 = 0; k0 < CIN; k0 += 32) {
        bf16x8 bfr[2];
#pragma unroll
        for (int ni = 0; ni < 2; ++ni) bfr[ni] = *(const bf16x8*)(Wp + (size_t)ni * 16 * CIN + k0);
#pragma unroll
        for (int mi = 0; mi < 4; ++mi) {
            bf16x8 a = *(const bf16x8*)(Al + mi * 16 * ASTRIDE + k0);
            acc[mi][0] = __builtin_amdgcn_mfma_f32_16x16x32_bf16(a, bfr[0], acc[mi][0], 0, 0, 0);
            acc[mi][1] = __builtin_amdgcn_mfma_f32_16x16x32_bf16(a, bfr[1], acc[mi][1], 0, 0, 0);
        }
    }
    // ---- epilogue: H store + per-block column stats (each column owned by one lane) ----
#pragma unroll
    for (int mi = 0; mi < 4; ++mi)
#pragma unroll
        for (int ni = 0; ni < 2; ++ni) {
            int col  = w * 32 + ni * 16 + l15;
            int rowb = row0 + mi * 16 + quad * 4;
#pragma unroll
            for (int r = 0; r < 4; ++r)
                H[(size_t)(rowb + r) * 256 + col] = (bf16_t)acc[mi][ni][r];
        }
#pragma unroll
    for (int ni = 0; ni < 2; ++ni) {
        float s = 0.0f, ss = 0.0f;
#pragma unroll
        for (int mi = 0; mi < 4; ++mi)
#pragma unroll
            for (int r = 0; r < 4; ++r) {
                float v = acc[mi][ni][r];
                s += v; ss = fmaf(v, v, ss);
            }
        s  += __shfl_xor(s, 16);  s  += __shfl_xor(s, 32);
        ss += __shfl_xor(ss, 16); ss += __shfl_xor(ss, 32);
        if (quad == 0) {
            int cl = w * 32 + ni * 16 + l15;      // unique per lane across block
            float* slot = P0 + (size_t)blockIdx.x * 512;
            slot[cl]       = s;
            slot[256 + cl] = ss;
        }
    }
}

// ---------------- GEMM2: A staged in LDS with fused BN+ReLU (1x), 8 col-waves (W 1x) ----------
// grid NP/64 = 1024 blocks.
__global__ __launch_bounds__(512) void gemm2_kernel(const bf16_t* __restrict__ A,
                                                    const bf16_t* __restrict__ Wt,
                                                    const float* __restrict__ scale,
                                                    const float* __restrict__ shift,
                                                    bf16_t* __restrict__ H,
                                                    float* __restrict__ P1) {
    const int K = M0;   // 256
    __shared__ bf16_t As2[64 * A2STRIDE];   // 33792 B
    __shared__ float ssc[256], ssh[256];    // 2 KB
    int row0 = blockIdx.x * 64;
    if (threadIdx.x < 256) { ssc[threadIdx.x] = scale[threadIdx.x]; ssh[threadIdx.x] = shift[threadIdx.x]; }
    __syncthreads();
    // stage A-tile: 64 rows x 256 ch, BN+ReLU applied once; coalesced 16B loads
#pragma unroll
    for (int rI = 0; rI < 4; ++rI) {
        int idx = rI * 512 + threadIdx.x;     // 0..2047
        int row = idx >> 5;
        int c8  = (idx & 31) * 8;
        bf16x8 raw = *(const bf16x8*)(A + (size_t)(row0 + row) * 256 + c8);
        bf16x8 t;
#pragma unroll
        for (int j = 0; j < 8; ++j)
            t[j] = (bf16_t)fmaxf(fmaf((float)raw[j], ssc[c8 + j], ssh[c8 + j]), 0.0f);
        *(bf16x8*)(As2 + row * A2STRIDE + c8) = t;
    }
    __syncthreads();
    int w    = threadIdx.x >> 6;
    int lane = threadIdx.x & 63;
    int l15  = lane & 15;
    int quad = lane >> 4;
    f32x4 acc[4][2] = {};
    const bf16_t* Wp = Wt + ((size_t)(w * 32) + l15) * K + quad * 8;
    const bf16_t* Al = As2 + l15 * A2STRIDE + quad * 8;
    for (int k0 = 0; k0 < K; k0 += 32) {
        bf16x8 bfr[2];
#pragma unroll
        for (int ni = 0; ni < 2; ++ni) bfr[ni] = *(const bf16x8*)(Wp + (size_t)ni * 16 * K + k0);
#pragma unroll
        for (int mi = 0; mi < 4; ++mi) {
            bf16x8 a = *(const bf16x8*)(Al + mi * 16 * A2STRIDE + k0);
            acc[mi][0] = __builtin_amdgcn_mfma_f32_16x16x32_bf16(a, bfr[0], acc[mi][0], 0, 0, 0);
            acc[mi][1] = __builtin_amdgcn_mfma_f32_16x16x32_bf16(a, bfr[1], acc[mi][1], 0, 0, 0);
        }
    }
#pragma unroll
    for (int mi = 0; mi < 4; ++mi)
#pragma unroll
        for (int ni = 0; ni < 2; ++ni) {
            int col  = w * 32 + ni * 16 + l15;
            int rowb = row0 + mi * 16 + quad * 4;
#pragma unroll
            for (int r = 0; r < 4; ++r)
                H[(size_t)(rowb + r) * 256 + col] = (bf16_t)acc[mi][ni][r];
        }
#pragma unroll
    for (int ni = 0; ni < 2; ++ni) {
        float s = 0.0f, ss = 0.0f;
#pragma unroll
        for (int mi = 0; mi < 4; ++mi)
#pragma unroll
            for (int r = 0; r < 4; ++r) {
                float v = acc[mi][ni][r];
                s += v; ss = fmaf(v, v, ss);
            }
        s  += __shfl_xor(s, 16);  s  += __shfl_xor(s, 32);
        ss += __shfl_xor(ss, 16); ss += __shfl_xor(ss, 32);
        if (quad == 0) {
            int cl = w * 32 + ni * 16 + l15;
            float* slot = P1 + (size_t)blockIdx.x * 512;
            slot[cl]       = s;
            slot[256 + cl] = ss;
        }
    }
}

// ---------------- reduce per-block partials -> scale/shift (one block per channel) ----------------
__global__ __launch_bounds__(256) void finalize_partials_kernel(const float* __restrict__ P, int nblk,
                                                                const float* __restrict__ gamma,
                                                                const float* __restrict__ beta,
                                                                float* __restrict__ scale,
                                                                float* __restrict__ shift) {
    int c = blockIdx.x;
    float s = 0.0f, ss = 0.0f;
    for (int bb = threadIdx.x; bb < nblk; bb += 256) {
        const float* row = P + (size_t)bb * 512;
        s  += row[c];
        ss += row[256 + c];
    }
#pragma unroll
    for (int k = 32; k >= 1; k >>= 1) { s += __shfl_xor(s, k); ss += __shfl_xor(ss, k); }
    __shared__ float as_[4], ass_[4];
    int w = threadIdx.x >> 6;
    if ((threadIdx.x & 63) == 0) { as_[w] = s; ass_[w] = ss; }
    __syncthreads();
    if (threadIdx.x == 0) {
        float S  = as_[0] + as_[1] + as_[2] + as_[3];
        float SS = ass_[0] + ass_[1] + ass_[2] + ass_[3];
        float m   = S * (1.0f / NP);
        float var = SS * (1.0f / NP) - m * m;
        float sc  = rsqrtf(var + 1e-5f) * gamma[c];
        scale[c] = sc;
        shift[c] = fmaf(-m, sc, beta[c]);
    }
}

// ---------------- final BN+ReLU: H1 bf16 -> fp32 d_out ----------------
__global__ void bnrelu_final_kernel(const bf16_t* __restrict__ H, const float* __restrict__ scale,
                                    const float* __restrict__ shift, float* __restrict__ out) {
    int tid = blockIdx.x * 256 + threadIdx.x;
    bf16x8 v = *(const bf16x8*)(H + (size_t)tid * 8);
    int c = (tid & 31) * 8;
    float4 o0, o1;
    o0.x = fmaxf(fmaf((float)v[0], scale[c + 0], shift[c + 0]), 0.0f);
    o0.y = fmaxf(fmaf((float)v[1], scale[c + 1], shift[c + 1]), 0.0f);
    o0.z = fmaxf(fmaf((float)v[2], scale[c + 2], shift[c + 2]), 0.0f);
    o0.w = fmaxf(fmaf((float)v[3], scale[c + 3], shift[c + 3]), 0.0f);
    o1.x = fmaxf(fmaf((float)v[4], scale[c + 4], shift[c + 4]), 0.0f);
    o1.y = fmaxf(fmaf((float)v[5], scale[c + 5], shift[c + 5]), 0.0f);
    o1.z = fmaxf(fmaf((float)v[6], scale[c + 6], shift[c + 6]), 0.0f);
    o1.w = fmaxf(fmaf((float)v[7], scale[c + 7], shift[c + 7]), 0.0f);
    ((float4*)out)[tid * 2]     = o0;
    ((float4*)out)[tid * 2 + 1] = o1;
}

extern "C" void kernel_launch(void* const* d_in, const int* in_sizes, int n_in,
                              void* d_out, int out_size, void* d_ws, size_t ws_size,
                              hipStream_t stream) {
    const float* xyz1    = (const float*)d_in[0];
    const float* xyz2    = (const float*)d_in[1];
    const float* points1 = (const float*)d_in[2];
    const float* points2 = (const float*)d_in[3];
    const float* W0      = (const float*)d_in[4];
    const float* g0      = (const float*)d_in[5];
    const float* b0      = (const float*)d_in[6];
    const float* W1      = (const float*)d_in[7];
    const float* g1      = (const float*)d_in[8];
    const float* b1      = (const float*)d_in[9];
    float* out = (float*)d_out;

    // ws layout (float offsets), ~85.8 MB
    float* wsf    = (float*)d_ws;
    float* scale0 = wsf + 0;
    float* shift0 = wsf + 256;
    float* scale1 = wsf + 512;
    float* shift1 = wsf + 768;
    float* w3     = wsf + 2048;                       // 196608 f
    int*   idx3   = (int*)(wsf + 198656);             // 196608 i
    bf16_t* Wb0   = (bf16_t*)(wsf + 395264);          // 98304 bf16
    bf16_t* Wb1   = (bf16_t*)(wsf + 444416);          // 65536 bf16
    float* pd     = wsf + 477184;                     // NP*48 f -> ends 3622912 (dead after merge)
    int*   pi     = (int*)(wsf + 3622912);            // NP*48 i -> ends 6768640, aliases H0 head (dead before gemm1)
    bf16_t* P2b   = (bf16_t*)(wsf + 477184);          // 4194304 bf16, aliases pd (cvt after merge)
    bf16_t* H0    = (bf16_t*)(wsf + 3622912);         // NP*256 bf16
    bf16_t* H1    = (bf16_t*)(wsf + 12011520);        // NP*256 bf16
    float* P0     = wsf + 20400128;                   // 1024*512 f
    float* P1     = wsf + 20924416;                   // 1024*512 f -> ends 21448704 f

    cvt_bf16_kernel<<<(M0 * CIN + 255) / 256, 256, 0, stream>>>(W0, Wb0, M0 * CIN);
    cvt_bf16_kernel<<<(M0 * M0 + 255) / 256, 256, 0, stream>>>(W1, Wb1, M0 * M0);

    nn3_partial_kernel<<<dim3(B_SZ * (N1 / 512), CHUNKS), 256, 0, stream>>>(xyz1, xyz2, pd, pi);
    nn3_merge_kernel<<<NP / 256, 256, 0, stream>>>(pd, pi, idx3, w3);

    // points2 -> bf16 (into the dead pd region)
    cvt_bf16x4_kernel<<<(B_SZ * N2 * C2 / 4) / 256, 256, 0, stream>>>(points2, P2b);

    // layer 0
    gemm1_fused_kernel<<<NP / 64, 512, 0, stream>>>(points1, P2b, idx3, w3, Wb0, H0, P0);
    finalize_partials_kernel<<<256, 256, 0, stream>>>(P0, NP / 64, g0, b0, scale0, shift0);

    // layer 1
    gemm2_kernel<<<NP / 64, 512, 0, stream>>>(H0, Wb1, scale0, shift0, H1, P1);
    finalize_partials_kernel<<<256, 256, 0, stream>>>(P1, NP / 64, g1, b1, scale1, shift1);

    // final BN+ReLU -> fp32 output
    bnrelu_final_kernel<<<NP * 256 / 8 / 256, 256, 0, stream>>>(H1, scale1, shift1, out);
}

// Round 9
// 262.473 us; speedup vs baseline: 1.0633x; 1.0393x over previous
//
#include <hip/hip_runtime.h>

#define B_SZ 8
#define N1 8192
#define N2 2048
#define C1 128
#define C2 256
#define CIN 384
#define M0 256
#define NP (B_SZ * N1)   // 65536
#define CHUNKS 8
#define CHUNK (N2 / CHUNKS)   // 256
#define ASTRIDE 392          // gemm1 A-tile LDS row stride (384+8 bf16)
#define A2STRIDE 264         // gemm2 A-tile LDS row stride (256+8 bf16)

typedef __bf16 bf16_t;
typedef bf16_t bf16x8 __attribute__((ext_vector_type(8)));
typedef bf16_t bf16x4 __attribute__((ext_vector_type(4)));
typedef float  f32x4  __attribute__((ext_vector_type(4)));

// ---------------- fp32 -> bf16 converts (W0+W1 fused into one launch) ----------------
__global__ void cvt_w_kernel(const float* __restrict__ W0, const float* __restrict__ W1,
                             bf16_t* __restrict__ o0, bf16_t* __restrict__ o1) {
    int i = blockIdx.x * 256 + threadIdx.x;      // 0 .. 163839
    if (i < M0 * CIN) o0[i] = (bf16_t)W0[i];
    else              o1[i - M0 * CIN] = (bf16_t)W1[i - M0 * CIN];
}
__global__ void cvt_bf16x4_kernel(const float* __restrict__ in, bf16_t* __restrict__ out) {
    int tid = blockIdx.x * 256 + threadIdx.x;
    float4 v = ((const float4*)in)[tid];
    bf16x4 o;
    o[0] = (bf16_t)v.x; o[1] = (bf16_t)v.y; o[2] = (bf16_t)v.z; o[3] = (bf16_t)v.w;
    ((bf16x4*)out)[tid] = o;
}

// ---------------- 3-NN partial: R0-exact form + wave-uniform insert skip ----------------
// Scoreboard R0..R7: the original form (62.2us) beat every restructure (med3 64.6,
// dual-chain 76.6, MQ2@halfocc 70.0, scalar 74.6, MQ2@fullocc 69.9). This keeps the
// R0 body byte-exact and adds ONE mechanism: skip the 13-inst insert when no lane
// can improve (__any(sq < d2) false => sq >= d2 >= d1 >= d0 for all lanes => all
// cndmasks provably no-ops). Wave-uniform branch (ballot-based), ~18% expected
// skip-rate at 256-candidate chunks. Selection semantics EXACTLY R0's.
__global__ __launch_bounds__(256) void nn3_partial_kernel(const float* __restrict__ xyz1,
                                                          const float* __restrict__ xyz2,
                                                          float* __restrict__ pd,
                                                          int* __restrict__ pi) {
    __shared__ float4 s2[CHUNK];   // 4 KB
    int b = blockIdx.x >> 5;
    int i = ((blockIdx.x & 31) << 8) + threadIdx.x;
    int c = blockIdx.y;
    const float* x2 = xyz2 + ((size_t)b * N2 + (size_t)c * CHUNK) * 3;
    {
        int j = threadIdx.x;
        float x = x2[j * 3 + 0], y = x2[j * 3 + 1], z = x2[j * 3 + 2];
        s2[j] = make_float4(x, y, z, x * x + y * y + z * z);
    }
    __syncthreads();
    const float* p = xyz1 + ((size_t)b * N1 + i) * 3;
    float px = p[0], py = p[1], pz = p[2];
    float pn = px * px + py * py + pz * pz;
    float d0 = 1e30f, d1 = 1e30f, d2 = 1e30f;
    int   j0 = 0,     j1 = 0,     j2 = 0;
#pragma unroll 4
    for (int j = 0; j < CHUNK; ++j) {
        float4 v = s2[j];
        float dot = fmaf(px, v.x, fmaf(py, v.y, pz * v.z));
        float sq  = fmaf(-2.0f, dot, pn + v.w);
        if (__any(sq < d2)) {
            bool c0 = sq < d0, c1 = sq < d1, c2 = sq < d2;
            d2 = c1 ? d1 : (c2 ? sq : d2);
            j2 = c1 ? j1 : (c2 ? j  : j2);
            d1 = c0 ? d0 : (c1 ? sq : d1);
            j1 = c0 ? j0 : (c1 ? j  : j1);
            d0 = c0 ? sq : d0;
            j0 = c0 ? j  : j0;
        }
    }
    int jb = c * CHUNK;
    size_t pidx = (size_t)b * N1 + i;
    pd[((size_t)c * 3 + 0) * NP + pidx] = d0;
    pd[((size_t)c * 3 + 1) * NP + pidx] = d1;
    pd[((size_t)c * 3 + 2) * NP + pidx] = d2;
    pi[((size_t)c * 3 + 0) * NP + pidx] = j0 + jb;
    pi[((size_t)c * 3 + 1) * NP + pidx] = j1 + jb;
    pi[((size_t)c * 3 + 2) * NP + pidx] = j2 + jb;
}

// ---------------- merge partials, sqrt + weights ----------------
__global__ void nn3_merge_kernel(const float* __restrict__ pd, const int* __restrict__ pi,
                                 int* __restrict__ idx3, float* __restrict__ w3) {
    int p = blockIdx.x * 256 + threadIdx.x;
    float d0 = 1e30f, d1 = 1e30f, d2 = 1e30f;
    int   j0 = 0,     j1 = 0,     j2 = 0;
#pragma unroll
    for (int k = 0; k < CHUNKS * 3; ++k) {
        float d = pd[(size_t)k * NP + p];
        int   j = pi[(size_t)k * NP + p];
        bool c0 = d < d0, c1 = d < d1, c2 = d < d2;
        d2 = c1 ? d1 : (c2 ? d : d2);
        j2 = c1 ? j1 : (c2 ? j : j2);
        d1 = c0 ? d0 : (c1 ? d : d1);
        j1 = c0 ? j0 : (c1 ? j : j1);
        d0 = c0 ? d : d0;
        j0 = c0 ? j : j0;
    }
    float r0 = sqrtf(fmaxf(d0, 0.0f));
    float r1 = sqrtf(fmaxf(d1, 0.0f));
    float r2 = sqrtf(fmaxf(d2, 0.0f));
    float inv0 = 1.0f / (r0 + 1e-8f);
    float inv1 = 1.0f / (r1 + 1e-8f);
    float inv2 = 1.0f / (r2 + 1e-8f);
    float s = inv0 + inv1 + inv2;
    size_t o = (size_t)p * 3;
    w3[o] = inv0 / s; w3[o + 1] = inv1 / s; w3[o + 2] = inv2 / s;
    idx3[o] = j0; idx3[o + 1] = j1; idx3[o + 2] = j2;
}

// ---------------- GEMM1 fused gather: bf16 points2, staged idx/w, 8 col-waves (W read 1x) ----
// grid NP/64 = 1024 blocks; batch->XCD swizzle (batch = blk&7).
__global__ __launch_bounds__(512) void gemm1_fused_kernel(const float* __restrict__ points1,
                                                          const bf16_t* __restrict__ P2b,
                                                          const int* __restrict__ idx3,
                                                          const float* __restrict__ w3,
                                                          const bf16_t* __restrict__ Wt,
                                                          bf16_t* __restrict__ H,
                                                          float* __restrict__ P0) {
    __shared__ bf16_t As[64 * ASTRIDE];   // 50176 B
    __shared__ int   si[192];             // 768 B
    __shared__ float sw[192];             // 768 B -> 51712 B total: 3 blocks/CU
    int bb   = blockIdx.x & 7;
    int tile = blockIdx.x >> 3;
    int row0 = bb * N1 + tile * 64;
    // stage idx/w coalesced
    if (threadIdx.x < 192)
        si[threadIdx.x] = idx3[(size_t)row0 * 3 + threadIdx.x];
    else if (threadIdx.x >= 256 && threadIdx.x < 448)
        sw[threadIdx.x - 256] = w3[(size_t)row0 * 3 + (threadIdx.x - 256)];
    __syncthreads();
    // ---- phase 1: interp (bf16 rows) + points1 copy into LDS; 8 threads/point ----
    {
        int pt  = threadIdx.x >> 3;
        int sub = threadIdx.x & 7;
        int i0 = si[pt * 3], i1 = si[pt * 3 + 1], i2 = si[pt * 3 + 2];
        float w0 = sw[pt * 3], w1 = sw[pt * 3 + 1], w2 = sw[pt * 3 + 2];
        const bf16_t* P2 = P2b + (size_t)bb * N2 * C2;
        const bf16_t* r0 = P2 + (size_t)i0 * C2;
        const bf16_t* r1 = P2 + (size_t)i1 * C2;
        const bf16_t* r2 = P2 + (size_t)i2 * C2;
        bf16_t* Ar = As + pt * ASTRIDE;
#pragma unroll
        for (int q = 0; q < 4; ++q) {
            int c = q * 64 + sub * 8;
            bf16x8 va = *(const bf16x8*)(r0 + c);
            bf16x8 vb = *(const bf16x8*)(r1 + c);
            bf16x8 vc = *(const bf16x8*)(r2 + c);
            bf16x8 o;
#pragma unroll
            for (int j = 0; j < 8; ++j)
                o[j] = (bf16_t)(w0 * (float)va[j] + w1 * (float)vb[j] + w2 * (float)vc[j]);
            *(bf16x8*)(Ar + c) = o;
        }
        const float* p1 = points1 + (size_t)(row0 + pt) * C1;
#pragma unroll
        for (int q = 0; q < 4; ++q) {
            int c = q * 32 + sub * 4;
            float4 v = *(const float4*)(p1 + c);
            bf16x4 o;
            o[0] = (bf16_t)v.x; o[1] = (bf16_t)v.y; o[2] = (bf16_t)v.z; o[3] = (bf16_t)v.w;
            *(bf16x4*)(Ar + C2 + c) = o;
        }
    }
    __syncthreads();
    // ---- phase 2: wave w -> cols [w*32, w*32+32), all 64 rows. W slice private to wave. ----
    int w    = threadIdx.x >> 6;
    int lane = threadIdx.x & 63;
    int l15  = lane & 15;
    int quad = lane >> 4;
    f32x4 acc[4][2] = {};
    const bf16_t* Wp = Wt + ((size_t)(w * 32) + l15) * CIN + quad * 8;
    const bf16_t* Al = As + l15 * ASTRIDE + quad * 8;
    for (int k0 = 0; k0 < CIN; k0 += 32) {
        bf16x8 bfr[2];
#pragma unroll
        for (int ni = 0; ni < 2; ++ni) bfr[ni] = *(const bf16x8*)(Wp + (size_t)ni * 16 * CIN + k0);
#pragma unroll
        for (int mi = 0; mi < 4; ++mi) {
            bf16x8 a = *(const bf16x8*)(Al + mi * 16 * ASTRIDE + k0);
            acc[mi][0] = __builtin_amdgcn_mfma_f32_16x16x32_bf16(a, bfr[0], acc[mi][0], 0, 0, 0);
            acc[mi][1] = __builtin_amdgcn_mfma_f32_16x16x32_bf16(a, bfr[1], acc[mi][1], 0, 0, 0);
        }
    }
    // ---- epilogue: H store + per-block column stats (each column owned by one lane) ----
#pragma unroll
    for (int mi = 0; mi < 4; ++mi)
#pragma unroll
        for (int ni = 0; ni < 2; ++ni) {
            int col  = w * 32 + ni * 16 + l15;
            int rowb = row0 + mi * 16 + quad * 4;
#pragma unroll
            for (int r = 0; r < 4; ++r)
                H[(size_t)(rowb + r) * 256 + col] = (bf16_t)acc[mi][ni][r];
        }
#pragma unroll
    for (int ni = 0; ni < 2; ++ni) {
        float s = 0.0f, ss = 0.0f;
#pragma unroll
        for (int mi = 0; mi < 4; ++mi)
#pragma unroll
            for (int r = 0; r < 4; ++r) {
                float v = acc[mi][ni][r];
                s += v; ss = fmaf(v, v, ss);
            }
        s  += __shfl_xor(s, 16);  s  += __shfl_xor(s, 32);
        ss += __shfl_xor(ss, 16); ss += __shfl_xor(ss, 32);
        if (quad == 0) {
            int cl = w * 32 + ni * 16 + l15;      // unique per lane across block
            float* slot = P0 + (size_t)blockIdx.x * 512;
            slot[cl]       = s;
            slot[256 + cl] = ss;
        }
    }
}

// ---------------- GEMM2: A staged in LDS with fused BN+ReLU (1x), 8 col-waves (W 1x) ----------
// grid NP/64 = 1024 blocks.
__global__ __launch_bounds__(512) void gemm2_kernel(const bf16_t* __restrict__ A,
                                                    const bf16_t* __restrict__ Wt,
                                                    const float* __restrict__ scale,
                                                    const float* __restrict__ shift,
                                                    bf16_t* __restrict__ H,
                                                    float* __restrict__ P1) {
    const int K = M0;   // 256
    __shared__ bf16_t As2[64 * A2STRIDE];   // 33792 B
    __shared__ float ssc[256], ssh[256];    // 2 KB
    int row0 = blockIdx.x * 64;
    if (threadIdx.x < 256) { ssc[threadIdx.x] = scale[threadIdx.x]; ssh[threadIdx.x] = shift[threadIdx.x]; }
    __syncthreads();
    // stage A-tile: 64 rows x 256 ch, BN+ReLU applied once; coalesced 16B loads
#pragma unroll
    for (int rI = 0; rI < 4; ++rI) {
        int idx = rI * 512 + threadIdx.x;     // 0..2047
        int row = idx >> 5;
        int c8  = (idx & 31) * 8;
        bf16x8 raw = *(const bf16x8*)(A + (size_t)(row0 + row) * 256 + c8);
        bf16x8 t;
#pragma unroll
        for (int j = 0; j < 8; ++j)
            t[j] = (bf16_t)fmaxf(fmaf((float)raw[j], ssc[c8 + j], ssh[c8 + j]), 0.0f);
        *(bf16x8*)(As2 + row * A2STRIDE + c8) = t;
    }
    __syncthreads();
    int w    = threadIdx.x >> 6;
    int lane = threadIdx.x & 63;
    int l15  = lane & 15;
    int quad = lane >> 4;
    f32x4 acc[4][2] = {};
    const bf16_t* Wp = Wt + ((size_t)(w * 32) + l15) * K + quad * 8;
    const bf16_t* Al = As2 + l15 * A2STRIDE + quad * 8;
    for (int k0 = 0; k0 < K; k0 += 32) {
        bf16x8 bfr[2];
#pragma unroll
        for (int ni = 0; ni < 2; ++ni) bfr[ni] = *(const bf16x8*)(Wp + (size_t)ni * 16 * K + k0);
#pragma unroll
        for (int mi = 0; mi < 4; ++mi) {
            bf16x8 a = *(const bf16x8*)(Al + mi * 16 * A2STRIDE + k0);
            acc[mi][0] = __builtin_amdgcn_mfma_f32_16x16x32_bf16(a, bfr[0], acc[mi][0], 0, 0, 0);
            acc[mi][1] = __builtin_amdgcn_mfma_f32_16x16x32_bf16(a, bfr[1], acc[mi][1], 0, 0, 0);
        }
    }
#pragma unroll
    for (int mi = 0; mi < 4; ++mi)
#pragma unroll
        for (int ni = 0; ni < 2; ++ni) {
            int col  = w * 32 + ni * 16 + l15;
            int rowb = row0 + mi * 16 + quad * 4;
#pragma unroll
            for (int r = 0; r < 4; ++r)
                H[(size_t)(rowb + r) * 256 + col] = (bf16_t)acc[mi][ni][r];
        }
#pragma unroll
    for (int ni = 0; ni < 2; ++ni) {
        float s = 0.0f, ss = 0.0f;
#pragma unroll
        for (int mi = 0; mi < 4; ++mi)
#pragma unroll
            for (int r = 0; r < 4; ++r) {
                float v = acc[mi][ni][r];
                s += v; ss = fmaf(v, v, ss);
            }
        s  += __shfl_xor(s, 16);  s  += __shfl_xor(s, 32);
        ss += __shfl_xor(ss, 16); ss += __shfl_xor(ss, 32);
        if (quad == 0) {
            int cl = w * 32 + ni * 16 + l15;
            float* slot = P1 + (size_t)blockIdx.x * 512;
            slot[cl]       = s;
            slot[256 + cl] = ss;
        }
    }
}

// ---------------- reduce per-block partials -> scale/shift (one block per channel) ----------------
__global__ __launch_bounds__(256) void finalize_partials_kernel(const float* __restrict__ P, int nblk,
                                                                const float* __restrict__ gamma,
                                                                const float* __restrict__ beta,
                                                                float* __restrict__ scale,
                                                                float* __restrict__ shift) {
    int c = blockIdx.x;
    float s = 0.0f, ss = 0.0f;
    for (int bb = threadIdx.x; bb < nblk; bb += 256) {
        const float* row = P + (size_t)bb * 512;
        s  += row[c];
        ss += row[256 + c];
    }
#pragma unroll
    for (int k = 32; k >= 1; k >>= 1) { s += __shfl_xor(s, k); ss += __shfl_xor(ss, k); }
    __shared__ float as_[4], ass_[4];
    int w = threadIdx.x >> 6;
    if ((threadIdx.x & 63) == 0) { as_[w] = s; ass_[w] = ss; }
    __syncthreads();
    if (threadIdx.x == 0) {
        float S  = as_[0] + as_[1] + as_[2] + as_[3];
        float SS = ass_[0] + ass_[1] + ass_[2] + ass_[3];
        float m   = S * (1.0f / NP);
        float var = SS * (1.0f / NP) - m * m;
        float sc  = rsqrtf(var + 1e-5f) * gamma[c];
        scale[c] = sc;
        shift[c] = fmaf(-m, sc, beta[c]);
    }
}

// ---------------- final BN+ReLU: H1 bf16 -> fp32 d_out ----------------
__global__ void bnrelu_final_kernel(const bf16_t* __restrict__ H, const float* __restrict__ scale,
                                    const float* __restrict__ shift, float* __restrict__ out) {
    int tid = blockIdx.x * 256 + threadIdx.x;
    bf16x8 v = *(const bf16x8*)(H + (size_t)tid * 8);
    int c = (tid & 31) * 8;
    float4 o0, o1;
    o0.x = fmaxf(fmaf((float)v[0], scale[c + 0], shift[c + 0]), 0.0f);
    o0.y = fmaxf(fmaf((float)v[1], scale[c + 1], shift[c + 1]), 0.0f);
    o0.z = fmaxf(fmaf((float)v[2], scale[c + 2], shift[c + 2]), 0.0f);
    o0.w = fmaxf(fmaf((float)v[3], scale[c + 3], shift[c + 3]), 0.0f);
    o1.x = fmaxf(fmaf((float)v[4], scale[c + 4], shift[c + 4]), 0.0f);
    o1.y = fmaxf(fmaf((float)v[5], scale[c + 5], shift[c + 5]), 0.0f);
    o1.z = fmaxf(fmaf((float)v[6], scale[c + 6], shift[c + 6]), 0.0f);
    o1.w = fmaxf(fmaf((float)v[7], scale[c + 7], shift[c + 7]), 0.0f);
    ((float4*)out)[tid * 2]     = o0;
    ((float4*)out)[tid * 2 + 1] = o1;
}

extern "C" void kernel_launch(void* const* d_in, const int* in_sizes, int n_in,
                              void* d_out, int out_size, void* d_ws, size_t ws_size,
                              hipStream_t stream) {
    const float* xyz1    = (const float*)d_in[0];
    const float* xyz2    = (const float*)d_in[1];
    const float* points1 = (const float*)d_in[2];
    const float* points2 = (const float*)d_in[3];
    const float* W0      = (const float*)d_in[4];
    const float* g0      = (const float*)d_in[5];
    const float* b0      = (const float*)d_in[6];
    const float* W1      = (const float*)d_in[7];
    const float* g1      = (const float*)d_in[8];
    const float* b1      = (const float*)d_in[9];
    float* out = (float*)d_out;

    // ws layout (float offsets), ~85.8 MB
    float* wsf    = (float*)d_ws;
    float* scale0 = wsf + 0;
    float* shift0 = wsf + 256;
    float* scale1 = wsf + 512;
    float* shift1 = wsf + 768;
    float* w3     = wsf + 2048;                       // 196608 f
    int*   idx3   = (int*)(wsf + 198656);             // 196608 i
    bf16_t* Wb0   = (bf16_t*)(wsf + 395264);          // 98304 bf16
    bf16_t* Wb1   = (bf16_t*)(wsf + 444416);          // 65536 bf16
    float* pd     = wsf + 477184;                     // NP*24 f (dead after merge)
    int*   pi     = (int*)(wsf + 2050048);            // NP*24 i
    bf16_t* P2b   = (bf16_t*)(wsf + 477184);          // 4194304 bf16, aliases pd (cvt after merge)
    bf16_t* H0    = (bf16_t*)(wsf + 3622912);         // NP*256 bf16
    bf16_t* H1    = (bf16_t*)(wsf + 12011520);        // NP*256 bf16
    float* P0     = wsf + 20400128;                   // 1024*512 f
    float* P1     = wsf + 20924416;                   // 1024*512 f -> ends 21448704 f

    cvt_w_kernel<<<(M0 * CIN + M0 * M0) / 256, 256, 0, stream>>>(W0, W1, Wb0, Wb1);

    nn3_partial_kernel<<<dim3(B_SZ * (N1 / 256), CHUNKS), 256, 0, stream>>>(xyz1, xyz2, pd, pi);
    nn3_merge_kernel<<<NP / 256, 256, 0, stream>>>(pd, pi, idx3, w3);

    // points2 -> bf16 (into the dead pd/pi region)
    cvt_bf16x4_kernel<<<(B_SZ * N2 * C2 / 4) / 256, 256, 0, stream>>>(points2, P2b);

    // layer 0
    gemm1_fused_kernel<<<NP / 64, 512, 0, stream>>>(points1, P2b, idx3, w3, Wb0, H0, P0);
    finalize_partials_kernel<<<256, 256, 0, stream>>>(P0, NP / 64, g0, b0, scale0, shift0);

    // layer 1
    gemm2_kernel<<<NP / 64, 512, 0, stream>>>(H0, Wb1, scale0, shift0, H1, P1);
    finalize_partials_kernel<<<256, 256, 0, stream>>>(P1, NP / 64, g1, b1, scale1, shift1);

    // final BN+ReLU -> fp32 output
    bnrelu_final_kernel<<<NP * 256 / 8 / 256, 256, 0, stream>>>(H1, scale1, shift1, out);
}

// Round 10
// 253.937 us; speedup vs baseline: 1.0991x; 1.0336x over previous
//
#include <hip/hip_runtime.h>

#define B_SZ 8
#define N1 8192
#define N2 2048
#define C1 128
#define C2 256
#define CIN 384
#define M0 256
#define NP (B_SZ * N1)   // 65536
#define CHUNKS 8
#define CHUNK (N2 / CHUNKS)   // 256
#define ASTRIDE 392          // gemm1 A-tile LDS row stride (384+8 bf16)
#define A2STRIDE 264         // gemm2 A-tile LDS row stride (256+8 bf16)
#define CSTRIDE 264          // C-tile staging stride (256+8 bf16)

typedef __bf16 bf16_t;
typedef bf16_t bf16x8 __attribute__((ext_vector_type(8)));
typedef bf16_t bf16x4 __attribute__((ext_vector_type(4)));
typedef float  f32x4  __attribute__((ext_vector_type(4)));

// ---------------- fp32 -> bf16 converts (W0+W1 fused into one launch) ----------------
__global__ void cvt_w_kernel(const float* __restrict__ W0, const float* __restrict__ W1,
                             bf16_t* __restrict__ o0, bf16_t* __restrict__ o1) {
    int i = blockIdx.x * 256 + threadIdx.x;      // 0 .. 163839
    if (i < M0 * CIN) o0[i] = (bf16_t)W0[i];
    else              o1[i - M0 * CIN] = (bf16_t)W1[i - M0 * CIN];
}
__global__ void cvt_bf16x4_kernel(const float* __restrict__ in, bf16_t* __restrict__ out) {
    int tid = blockIdx.x * 256 + threadIdx.x;
    float4 v = ((const float4*)in)[tid];
    bf16x4 o;
    o[0] = (bf16_t)v.x; o[1] = (bf16_t)v.y; o[2] = (bf16_t)v.z; o[3] = (bf16_t)v.w;
    ((bf16x4*)out)[tid] = o;
}

// ---------------- 3-NN partial: R0-exact form + wave-uniform insert skip (R8, 60.8us) ----
__global__ __launch_bounds__(256) void nn3_partial_kernel(const float* __restrict__ xyz1,
                                                          const float* __restrict__ xyz2,
                                                          float* __restrict__ pd,
                                                          int* __restrict__ pi) {
    __shared__ float4 s2[CHUNK];   // 4 KB
    int b = blockIdx.x >> 5;
    int i = ((blockIdx.x & 31) << 8) + threadIdx.x;
    int c = blockIdx.y;
    const float* x2 = xyz2 + ((size_t)b * N2 + (size_t)c * CHUNK) * 3;
    {
        int j = threadIdx.x;
        float x = x2[j * 3 + 0], y = x2[j * 3 + 1], z = x2[j * 3 + 2];
        s2[j] = make_float4(x, y, z, x * x + y * y + z * z);
    }
    __syncthreads();
    const float* p = xyz1 + ((size_t)b * N1 + i) * 3;
    float px = p[0], py = p[1], pz = p[2];
    float pn = px * px + py * py + pz * pz;
    float d0 = 1e30f, d1 = 1e30f, d2 = 1e30f;
    int   j0 = 0,     j1 = 0,     j2 = 0;
#pragma unroll 4
    for (int j = 0; j < CHUNK; ++j) {
        float4 v = s2[j];
        float dot = fmaf(px, v.x, fmaf(py, v.y, pz * v.z));
        float sq  = fmaf(-2.0f, dot, pn + v.w);
        if (__any(sq < d2)) {
            bool c0 = sq < d0, c1 = sq < d1, c2 = sq < d2;
            d2 = c1 ? d1 : (c2 ? sq : d2);
            j2 = c1 ? j1 : (c2 ? j  : j2);
            d1 = c0 ? d0 : (c1 ? sq : d1);
            j1 = c0 ? j0 : (c1 ? j  : j1);
            d0 = c0 ? sq : d0;
            j0 = c0 ? j  : j0;
        }
    }
    int jb = c * CHUNK;
    size_t pidx = (size_t)b * N1 + i;
    pd[((size_t)c * 3 + 0) * NP + pidx] = d0;
    pd[((size_t)c * 3 + 1) * NP + pidx] = d1;
    pd[((size_t)c * 3 + 2) * NP + pidx] = d2;
    pi[((size_t)c * 3 + 0) * NP + pidx] = j0 + jb;
    pi[((size_t)c * 3 + 1) * NP + pidx] = j1 + jb;
    pi[((size_t)c * 3 + 2) * NP + pidx] = j2 + jb;
}

// ---------------- merge partials, sqrt + weights ----------------
__global__ void nn3_merge_kernel(const float* __restrict__ pd, const int* __restrict__ pi,
                                 int* __restrict__ idx3, float* __restrict__ w3) {
    int p = blockIdx.x * 256 + threadIdx.x;
    float d0 = 1e30f, d1 = 1e30f, d2 = 1e30f;
    int   j0 = 0,     j1 = 0,     j2 = 0;
#pragma unroll
    for (int k = 0; k < CHUNKS * 3; ++k) {
        float d = pd[(size_t)k * NP + p];
        int   j = pi[(size_t)k * NP + p];
        bool c0 = d < d0, c1 = d < d1, c2 = d < d2;
        d2 = c1 ? d1 : (c2 ? d : d2);
        j2 = c1 ? j1 : (c2 ? j : j2);
        d1 = c0 ? d0 : (c1 ? d : d1);
        j1 = c0 ? j0 : (c1 ? j : j1);
        d0 = c0 ? d : d0;
        j0 = c0 ? j : j0;
    }
    float r0 = sqrtf(fmaxf(d0, 0.0f));
    float r1 = sqrtf(fmaxf(d1, 0.0f));
    float r2 = sqrtf(fmaxf(d2, 0.0f));
    float inv0 = 1.0f / (r0 + 1e-8f);
    float inv1 = 1.0f / (r1 + 1e-8f);
    float inv2 = 1.0f / (r2 + 1e-8f);
    float s = inv0 + inv1 + inv2;
    size_t o = (size_t)p * 3;
    w3[o] = inv0 / s; w3[o + 1] = inv1 / s; w3[o + 2] = inv2 / s;
    idx3[o] = j0; idx3[o + 1] = j1; idx3[o + 2] = j2;
}

// ---------------- GEMM1 fused gather: bf16 points2, staged idx/w, 8 col-waves (W read 1x) ----
// grid NP/64 = 1024 blocks; batch->XCD swizzle (batch = blk&7).
// Epilogue: C staged through LDS (reusing As) -> coalesced bf16x8 stores (was 32 scalar
// 2B strided stores per lane; now 4 dwordx4 per thread, 512B contiguous per wave).
__global__ __launch_bounds__(512) void gemm1_fused_kernel(const float* __restrict__ points1,
                                                          const bf16_t* __restrict__ P2b,
                                                          const int* __restrict__ idx3,
                                                          const float* __restrict__ w3,
                                                          const bf16_t* __restrict__ Wt,
                                                          bf16_t* __restrict__ H,
                                                          float* __restrict__ P0) {
    __shared__ bf16_t As[64 * ASTRIDE];   // 50176 B
    __shared__ int   si[192];             // 768 B
    __shared__ float sw[192];             // 768 B -> 51712 B total: 3 blocks/CU
    int bb   = blockIdx.x & 7;
    int tile = blockIdx.x >> 3;
    int row0 = bb * N1 + tile * 64;
    // stage idx/w coalesced
    if (threadIdx.x < 192)
        si[threadIdx.x] = idx3[(size_t)row0 * 3 + threadIdx.x];
    else if (threadIdx.x >= 256 && threadIdx.x < 448)
        sw[threadIdx.x - 256] = w3[(size_t)row0 * 3 + (threadIdx.x - 256)];
    __syncthreads();
    // ---- phase 1: interp (bf16 rows) + points1 copy into LDS; 8 threads/point ----
    {
        int pt  = threadIdx.x >> 3;
        int sub = threadIdx.x & 7;
        int i0 = si[pt * 3], i1 = si[pt * 3 + 1], i2 = si[pt * 3 + 2];
        float w0 = sw[pt * 3], w1 = sw[pt * 3 + 1], w2 = sw[pt * 3 + 2];
        const bf16_t* P2 = P2b + (size_t)bb * N2 * C2;
        const bf16_t* r0 = P2 + (size_t)i0 * C2;
        const bf16_t* r1 = P2 + (size_t)i1 * C2;
        const bf16_t* r2 = P2 + (size_t)i2 * C2;
        bf16_t* Ar = As + pt * ASTRIDE;
#pragma unroll
        for (int q = 0; q < 4; ++q) {
            int c = q * 64 + sub * 8;
            bf16x8 va = *(const bf16x8*)(r0 + c);
            bf16x8 vb = *(const bf16x8*)(r1 + c);
            bf16x8 vc = *(const bf16x8*)(r2 + c);
            bf16x8 o;
#pragma unroll
            for (int j = 0; j < 8; ++j)
                o[j] = (bf16_t)(w0 * (float)va[j] + w1 * (float)vb[j] + w2 * (float)vc[j]);
            *(bf16x8*)(Ar + c) = o;
        }
        const float* p1 = points1 + (size_t)(row0 + pt) * C1;
#pragma unroll
        for (int q = 0; q < 4; ++q) {
            int c = q * 32 + sub * 4;
            float4 v = *(const float4*)(p1 + c);
            bf16x4 o;
            o[0] = (bf16_t)v.x; o[1] = (bf16_t)v.y; o[2] = (bf16_t)v.z; o[3] = (bf16_t)v.w;
            *(bf16x4*)(Ar + C2 + c) = o;
        }
    }
    __syncthreads();
    // ---- phase 2: wave w -> cols [w*32, w*32+32), all 64 rows. W slice private to wave. ----
    int w    = threadIdx.x >> 6;
    int lane = threadIdx.x & 63;
    int l15  = lane & 15;
    int quad = lane >> 4;
    f32x4 acc[4][2] = {};
    const bf16_t* Wp = Wt + ((size_t)(w * 32) + l15) * CIN + quad * 8;
    const bf16_t* Al = As + l15 * ASTRIDE + quad * 8;
    for (int k0 = 0; k0 < CIN; k0 += 32) {
        bf16x8 bfr[2];
#pragma unroll
        for (int ni = 0; ni < 2; ++ni) bfr[ni] = *(const bf16x8*)(Wp + (size_t)ni * 16 * CIN + k0);
#pragma unroll
        for (int mi = 0; mi < 4; ++mi) {
            bf16x8 a = *(const bf16x8*)(Al + mi * 16 * ASTRIDE + k0);
            acc[mi][0] = __builtin_amdgcn_mfma_f32_16x16x32_bf16(a, bfr[0], acc[mi][0], 0, 0, 0);
            acc[mi][1] = __builtin_amdgcn_mfma_f32_16x16x32_bf16(a, bfr[1], acc[mi][1], 0, 0, 0);
        }
    }
    // ---- per-block column stats first (reads acc only) ----
#pragma unroll
    for (int ni = 0; ni < 2; ++ni) {
        float s = 0.0f, ss = 0.0f;
#pragma unroll
        for (int mi = 0; mi < 4; ++mi)
#pragma unroll
            for (int r = 0; r < 4; ++r) {
                float v = acc[mi][ni][r];
                s += v; ss = fmaf(v, v, ss);
            }
        s  += __shfl_xor(s, 16);  s  += __shfl_xor(s, 32);
        ss += __shfl_xor(ss, 16); ss += __shfl_xor(ss, 32);
        if (quad == 0) {
            int cl = w * 32 + ni * 16 + l15;      // unique per lane across block
            float* slot = P0 + (size_t)blockIdx.x * 512;
            slot[cl]       = s;
            slot[256 + cl] = ss;
        }
    }
    // ---- epilogue: stage C in LDS (As reuse; all k-loop reads done), coalesced store ----
    __syncthreads();
#pragma unroll
    for (int mi = 0; mi < 4; ++mi)
#pragma unroll
        for (int ni = 0; ni < 2; ++ni) {
            int col = w * 32 + ni * 16 + l15;
            int rw  = mi * 16 + quad * 4;
#pragma unroll
            for (int r = 0; r < 4; ++r)
                As[(rw + r) * CSTRIDE + col] = (bf16_t)acc[mi][ni][r];
        }
    __syncthreads();
#pragma unroll
    for (int rI = 0; rI < 4; ++rI) {
        int idx = rI * 512 + threadIdx.x;     // 0..2047
        int row = idx >> 5;
        int c8  = (idx & 31) * 8;
        *(bf16x8*)(H + (size_t)(row0 + row) * 256 + c8) = *(const bf16x8*)(As + row * CSTRIDE + c8);
    }
}

// ---------------- GEMM2: A staged in LDS with fused BN+ReLU (1x), 8 col-waves (W 1x) ----------
// grid NP/64 = 1024 blocks. Same coalesced LDS-staged epilogue as gemm1.
__global__ __launch_bounds__(512) void gemm2_kernel(const bf16_t* __restrict__ A,
                                                    const bf16_t* __restrict__ Wt,
                                                    const float* __restrict__ scale,
                                                    const float* __restrict__ shift,
                                                    bf16_t* __restrict__ H,
                                                    float* __restrict__ P1) {
    const int K = M0;   // 256
    __shared__ bf16_t As2[64 * A2STRIDE];   // 33792 B
    __shared__ float ssc[256], ssh[256];    // 2 KB
    int row0 = blockIdx.x * 64;
    if (threadIdx.x < 256) { ssc[threadIdx.x] = scale[threadIdx.x]; ssh[threadIdx.x] = shift[threadIdx.x]; }
    __syncthreads();
    // stage A-tile: 64 rows x 256 ch, BN+ReLU applied once; coalesced 16B loads
#pragma unroll
    for (int rI = 0; rI < 4; ++rI) {
        int idx = rI * 512 + threadIdx.x;     // 0..2047
        int row = idx >> 5;
        int c8  = (idx & 31) * 8;
        bf16x8 raw = *(const bf16x8*)(A + (size_t)(row0 + row) * 256 + c8);
        bf16x8 t;
#pragma unroll
        for (int j = 0; j < 8; ++j)
            t[j] = (bf16_t)fmaxf(fmaf((float)raw[j], ssc[c8 + j], ssh[c8 + j]), 0.0f);
        *(bf16x8*)(As2 + row * A2STRIDE + c8) = t;
    }
    __syncthreads();
    int w    = threadIdx.x >> 6;
    int lane = threadIdx.x & 63;
    int l15  = lane & 15;
    int quad = lane >> 4;
    f32x4 acc[4][2] = {};
    const bf16_t* Wp = Wt + ((size_t)(w * 32) + l15) * K + quad * 8;
    const bf16_t* Al = As2 + l15 * A2STRIDE + quad * 8;
    for (int k0 = 0; k0 < K; k0 += 32) {
        bf16x8 bfr[2];
#pragma unroll
        for (int ni = 0; ni < 2; ++ni) bfr[ni] = *(const bf16x8*)(Wp + (size_t)ni * 16 * K + k0);
#pragma unroll
        for (int mi = 0; mi < 4; ++mi) {
            bf16x8 a = *(const bf16x8*)(Al + mi * 16 * A2STRIDE + k0);
            acc[mi][0] = __builtin_amdgcn_mfma_f32_16x16x32_bf16(a, bfr[0], acc[mi][0], 0, 0, 0);
            acc[mi][1] = __builtin_amdgcn_mfma_f32_16x16x32_bf16(a, bfr[1], acc[mi][1], 0, 0, 0);
        }
    }
    // ---- per-block column stats first (reads acc only) ----
#pragma unroll
    for (int ni = 0; ni < 2; ++ni) {
        float s = 0.0f, ss = 0.0f;
#pragma unroll
        for (int mi = 0; mi < 4; ++mi)
#pragma unroll
            for (int r = 0; r < 4; ++r) {
                float v = acc[mi][ni][r];
                s += v; ss = fmaf(v, v, ss);
            }
        s  += __shfl_xor(s, 16);  s  += __shfl_xor(s, 32);
        ss += __shfl_xor(ss, 16); ss += __shfl_xor(ss, 32);
        if (quad == 0) {
            int cl = w * 32 + ni * 16 + l15;
            float* slot = P1 + (size_t)blockIdx.x * 512;
            slot[cl]       = s;
            slot[256 + cl] = ss;
        }
    }
    // ---- epilogue: stage C in LDS (As2 reuse; all k-loop reads done), coalesced store ----
    __syncthreads();
#pragma unroll
    for (int mi = 0; mi < 4; ++mi)
#pragma unroll
        for (int ni = 0; ni < 2; ++ni) {
            int col = w * 32 + ni * 16 + l15;
            int rw  = mi * 16 + quad * 4;
#pragma unroll
            for (int r = 0; r < 4; ++r)
                As2[(rw + r) * CSTRIDE + col] = (bf16_t)acc[mi][ni][r];
        }
    __syncthreads();
#pragma unroll
    for (int rI = 0; rI < 4; ++rI) {
        int idx = rI * 512 + threadIdx.x;     // 0..2047
        int row = idx >> 5;
        int c8  = (idx & 31) * 8;
        *(bf16x8*)(H + (size_t)(row0 + row) * 256 + c8) = *(const bf16x8*)(As2 + row * CSTRIDE + c8);
    }
}

// ---------------- reduce per-block partials -> scale/shift (one block per channel) ----------------
__global__ __launch_bounds__(256) void finalize_partials_kernel(const float* __restrict__ P, int nblk,
                                                                const float* __restrict__ gamma,
                                                                const float* __restrict__ beta,
                                                                float* __restrict__ scale,
                                                                float* __restrict__ shift) {
    int c = blockIdx.x;
    float s = 0.0f, ss = 0.0f;
    for (int bb = threadIdx.x; bb < nblk; bb += 256) {
        const float* row = P + (size_t)bb * 512;
        s  += row[c];
        ss += row[256 + c];
    }
#pragma unroll
    for (int k = 32; k >= 1; k >>= 1) { s += __shfl_xor(s, k); ss += __shfl_xor(ss, k); }
    __shared__ float as_[4], ass_[4];
    int w = threadIdx.x >> 6;
    if ((threadIdx.x & 63) == 0) { as_[w] = s; ass_[w] = ss; }
    __syncthreads();
    if (threadIdx.x == 0) {
        float S  = as_[0] + as_[1] + as_[2] + as_[3];
        float SS = ass_[0] + ass_[1] + ass_[2] + ass_[3];
        float m   = S * (1.0f / NP);
        float var = SS * (1.0f / NP) - m * m;
        float sc  = rsqrtf(var + 1e-5f) * gamma[c];
        scale[c] = sc;
        shift[c] = fmaf(-m, sc, beta[c]);
    }
}

// ---------------- final BN+ReLU: H1 bf16 -> fp32 d_out ----------------
__global__ void bnrelu_final_kernel(const bf16_t* __restrict__ H, const float* __restrict__ scale,
                                    const float* __restrict__ shift, float* __restrict__ out) {
    int tid = blockIdx.x * 256 + threadIdx.x;
    bf16x8 v = *(const bf16x8*)(H + (size_t)tid * 8);
    int c = (tid & 31) * 8;
    float4 o0, o1;
    o0.x = fmaxf(fmaf((float)v[0], scale[c + 0], shift[c + 0]), 0.0f);
    o0.y = fmaxf(fmaf((float)v[1], scale[c + 1], shift[c + 1]), 0.0f);
    o0.z = fmaxf(fmaf((float)v[2], scale[c + 2], shift[c + 2]), 0.0f);
    o0.w = fmaxf(fmaf((float)v[3], scale[c + 3], shift[c + 3]), 0.0f);
    o1.x = fmaxf(fmaf((float)v[4], scale[c + 4], shift[c + 4]), 0.0f);
    o1.y = fmaxf(fmaf((float)v[5], scale[c + 5], shift[c + 5]), 0.0f);
    o1.z = fmaxf(fmaf((float)v[6], scale[c + 6], shift[c + 6]), 0.0f);
    o1.w = fmaxf(fmaf((float)v[7], scale[c + 7], shift[c + 7]), 0.0f);
    ((float4*)out)[tid * 2]     = o0;
    ((float4*)out)[tid * 2 + 1] = o1;
}

extern "C" void kernel_launch(void* const* d_in, const int* in_sizes, int n_in,
                              void* d_out, int out_size, void* d_ws, size_t ws_size,
                              hipStream_t stream) {
    const float* xyz1    = (const float*)d_in[0];
    const float* xyz2    = (const float*)d_in[1];
    const float* points1 = (const float*)d_in[2];
    const float* points2 = (const float*)d_in[3];
    const float* W0      = (const float*)d_in[4];
    const float* g0      = (const float*)d_in[5];
    const float* b0      = (const float*)d_in[6];
    const float* W1      = (const float*)d_in[7];
    const float* g1      = (const float*)d_in[8];
    const float* b1      = (const float*)d_in[9];
    float* out = (float*)d_out;

    // ws layout (float offsets), ~85.8 MB
    float* wsf    = (float*)d_ws;
    float* scale0 = wsf + 0;
    float* shift0 = wsf + 256;
    float* scale1 = wsf + 512;
    float* shift1 = wsf + 768;
    float* w3     = wsf + 2048;                       // 196608 f
    int*   idx3   = (int*)(wsf + 198656);             // 196608 i
    bf16_t* Wb0   = (bf16_t*)(wsf + 395264);          // 98304 bf16
    bf16_t* Wb1   = (bf16_t*)(wsf + 444416);          // 65536 bf16
    float* pd     = wsf + 477184;                     // NP*24 f (dead after merge)
    int*   pi     = (int*)(wsf + 2050048);            // NP*24 i
    bf16_t* P2b   = (bf16_t*)(wsf + 477184);          // 4194304 bf16, aliases pd (cvt after merge)
    bf16_t* H0    = (bf16_t*)(wsf + 3622912);         // NP*256 bf16
    bf16_t* H1    = (bf16_t*)(wsf + 12011520);        // NP*256 bf16
    float* P0     = wsf + 20400128;                   // 1024*512 f
    float* P1     = wsf + 20924416;                   // 1024*512 f -> ends 21448704 f

    cvt_w_kernel<<<(M0 * CIN + M0 * M0) / 256, 256, 0, stream>>>(W0, W1, Wb0, Wb1);

    nn3_partial_kernel<<<dim3(B_SZ * (N1 / 256), CHUNKS), 256, 0, stream>>>(xyz1, xyz2, pd, pi);
    nn3_merge_kernel<<<NP / 256, 256, 0, stream>>>(pd, pi, idx3, w3);

    // points2 -> bf16 (into the dead pd/pi region)
    cvt_bf16x4_kernel<<<(B_SZ * N2 * C2 / 4) / 256, 256, 0, stream>>>(points2, P2b);

    // layer 0
    gemm1_fused_kernel<<<NP / 64, 512, 0, stream>>>(points1, P2b, idx3, w3, Wb0, H0, P0);
    finalize_partials_kernel<<<256, 256, 0, stream>>>(P0, NP / 64, g0, b0, scale0, shift0);

    // layer 1
    gemm2_kernel<<<NP / 64, 512, 0, stream>>>(H0, Wb1, scale0, shift0, H1, P1);
    finalize_partials_kernel<<<256, 256, 0, stream>>>(P1, NP / 64, g1, b1, scale1, shift1);

    // final BN+ReLU -> fp32 output
    bnrelu_final_kernel<<<NP * 256 / 8 / 256, 256, 0, stream>>>(H1, scale1, shift1, out);
}

// Round 12
// 248.044 us; speedup vs baseline: 1.1252x; 1.0238x over previous
//
#include <hip/hip_runtime.h>

#define B_SZ 8
#define N1 8192
#define N2 2048
#define C1 128
#define C2 256
#define CIN 384
#define M0 256
#define NP (B_SZ * N1)   // 65536
#define CHUNKS 8
#define CHUNK (N2 / CHUNKS)   // 256
#define ASTRIDE 392          // gemm1 A-tile LDS row stride (384+8 bf16)
#define A2STRIDE 264         // gemm2 A-tile LDS row stride (256+8 bf16)
#define CSTRIDE 264          // C-tile staging stride (256+8 bf16)

// front_kernel block ranges
#define NN3_BLKS   2048      // 256 blocks x 8 chunks (grid.x was 256, NOT 2048 -- R10 bug)
#define P2B_BLKS   4096      // (B*N2*C2/4)/256
#define W_BLKS     640       // (M0*CIN + M0*M0)/256

typedef __bf16 bf16_t;
typedef bf16_t bf16x8 __attribute__((ext_vector_type(8)));
typedef bf16_t bf16x4 __attribute__((ext_vector_type(4)));
typedef float  f32x4  __attribute__((ext_vector_type(4)));

// ---------------- fused front end: nn3_partial + points2->bf16 + W converts ----------------
// Launch-count reduction (9 -> 7): the three independent front kernels share one
// dispatch via block-range dispatch (block-uniform branch). nn3 body is byte-identical
// to the R8 version (60.8us: R0 form + __any(sq<d2) insert skip). cvt blocks
// co-schedule with VALU-bound nn3 blocks, absorbing their ~5us serial time.
__global__ __launch_bounds__(256) void front_kernel(const float* __restrict__ xyz1,
                                                    const float* __restrict__ xyz2,
                                                    const float* __restrict__ points2,
                                                    const float* __restrict__ W0,
                                                    const float* __restrict__ W1,
                                                    bf16_t* __restrict__ P2b,
                                                    bf16_t* __restrict__ Wb0,
                                                    bf16_t* __restrict__ Wb1,
                                                    float* __restrict__ pd,
                                                    int* __restrict__ pi) {
    __shared__ float4 s2[CHUNK];   // 4 KB (only used by nn3 blocks)
    int bid = blockIdx.x;
    if (bid < NN3_BLKS) {
        // ---- nn3 partial: c = bid&7, bx = bid>>3 in [0,256) (bijective remap of old (x,y)) ----
        int bx = bid >> 3;                // 0..255  == old blockIdx.x
        int c  = bid & 7;                 // 0..7    == old blockIdx.y
        int b  = bx >> 5;                 // 0..7    batch
        int i  = ((bx & 31) << 8) + threadIdx.x;   // 0..8191 query
        const float* x2 = xyz2 + ((size_t)b * N2 + (size_t)c * CHUNK) * 3;
        {
            int j = threadIdx.x;
            float x = x2[j * 3 + 0], y = x2[j * 3 + 1], z = x2[j * 3 + 2];
            s2[j] = make_float4(x, y, z, x * x + y * y + z * z);
        }
        __syncthreads();
        const float* p = xyz1 + ((size_t)b * N1 + i) * 3;
        float px = p[0], py = p[1], pz = p[2];
        float pn = px * px + py * py + pz * pz;
        float d0 = 1e30f, d1 = 1e30f, d2 = 1e30f;
        int   j0 = 0,     j1 = 0,     j2 = 0;
#pragma unroll 4
        for (int j = 0; j < CHUNK; ++j) {
            float4 v = s2[j];
            float dot = fmaf(px, v.x, fmaf(py, v.y, pz * v.z));
            float sq  = fmaf(-2.0f, dot, pn + v.w);
            if (__any(sq < d2)) {
                bool c0 = sq < d0, c1 = sq < d1, c2 = sq < d2;
                d2 = c1 ? d1 : (c2 ? sq : d2);
                j2 = c1 ? j1 : (c2 ? j  : j2);
                d1 = c0 ? d0 : (c1 ? sq : d1);
                j1 = c0 ? j0 : (c1 ? j  : j1);
                d0 = c0 ? sq : d0;
                j0 = c0 ? j  : j0;
            }
        }
        int jb = c * CHUNK;
        size_t pidx = (size_t)b * N1 + i;
        pd[((size_t)c * 3 + 0) * NP + pidx] = d0;
        pd[((size_t)c * 3 + 1) * NP + pidx] = d1;
        pd[((size_t)c * 3 + 2) * NP + pidx] = d2;
        pi[((size_t)c * 3 + 0) * NP + pidx] = j0 + jb;
        pi[((size_t)c * 3 + 1) * NP + pidx] = j1 + jb;
        pi[((size_t)c * 3 + 2) * NP + pidx] = j2 + jb;
    } else if (bid < NN3_BLKS + P2B_BLKS) {
        // ---- points2 -> bf16 (vectorized) ----
        int tid = (bid - NN3_BLKS) * 256 + threadIdx.x;
        float4 v = ((const float4*)points2)[tid];
        bf16x4 o;
        o[0] = (bf16_t)v.x; o[1] = (bf16_t)v.y; o[2] = (bf16_t)v.z; o[3] = (bf16_t)v.w;
        ((bf16x4*)P2b)[tid] = o;
    } else {
        // ---- W0+W1 -> bf16 ----
        int i = (bid - NN3_BLKS - P2B_BLKS) * 256 + threadIdx.x;
        if (i < M0 * CIN) Wb0[i] = (bf16_t)W0[i];
        else              Wb1[i - M0 * CIN] = (bf16_t)W1[i - M0 * CIN];
    }
}

// ---------------- merge partials, sqrt + weights ----------------
__global__ void nn3_merge_kernel(const float* __restrict__ pd, const int* __restrict__ pi,
                                 int* __restrict__ idx3, float* __restrict__ w3) {
    int p = blockIdx.x * 256 + threadIdx.x;
    float d0 = 1e30f, d1 = 1e30f, d2 = 1e30f;
    int   j0 = 0,     j1 = 0,     j2 = 0;
#pragma unroll
    for (int k = 0; k < CHUNKS * 3; ++k) {
        float d = pd[(size_t)k * NP + p];
        int   j = pi[(size_t)k * NP + p];
        bool c0 = d < d0, c1 = d < d1, c2 = d < d2;
        d2 = c1 ? d1 : (c2 ? d : d2);
        j2 = c1 ? j1 : (c2 ? j : j2);
        d1 = c0 ? d0 : (c1 ? d : d1);
        j1 = c0 ? j0 : (c1 ? j : j1);
        d0 = c0 ? d : d0;
        j0 = c0 ? j : j0;
    }
    float r0 = sqrtf(fmaxf(d0, 0.0f));
    float r1 = sqrtf(fmaxf(d1, 0.0f));
    float r2 = sqrtf(fmaxf(d2, 0.0f));
    float inv0 = 1.0f / (r0 + 1e-8f);
    float inv1 = 1.0f / (r1 + 1e-8f);
    float inv2 = 1.0f / (r2 + 1e-8f);
    float s = inv0 + inv1 + inv2;
    size_t o = (size_t)p * 3;
    w3[o] = inv0 / s; w3[o + 1] = inv1 / s; w3[o + 2] = inv2 / s;
    idx3[o] = j0; idx3[o + 1] = j1; idx3[o + 2] = j2;
}

// ---------------- GEMM1 fused gather: bf16 points2, staged idx/w, 8 col-waves (W read 1x) ----
// grid NP/64 = 1024 blocks; batch->XCD swizzle (batch = blk&7).
// Epilogue: C staged through LDS (reusing As) -> coalesced bf16x8 stores.
__global__ __launch_bounds__(512) void gemm1_fused_kernel(const float* __restrict__ points1,
                                                          const bf16_t* __restrict__ P2b,
                                                          const int* __restrict__ idx3,
                                                          const float* __restrict__ w3,
                                                          const bf16_t* __restrict__ Wt,
                                                          bf16_t* __restrict__ H,
                                                          float* __restrict__ P0) {
    __shared__ bf16_t As[64 * ASTRIDE];   // 50176 B
    __shared__ int   si[192];             // 768 B
    __shared__ float sw[192];             // 768 B -> 51712 B total: 3 blocks/CU
    int bb   = blockIdx.x & 7;
    int tile = blockIdx.x >> 3;
    int row0 = bb * N1 + tile * 64;
    // stage idx/w coalesced
    if (threadIdx.x < 192)
        si[threadIdx.x] = idx3[(size_t)row0 * 3 + threadIdx.x];
    else if (threadIdx.x >= 256 && threadIdx.x < 448)
        sw[threadIdx.x - 256] = w3[(size_t)row0 * 3 + (threadIdx.x - 256)];
    __syncthreads();
    // ---- phase 1: interp (bf16 rows) + points1 copy into LDS; 8 threads/point ----
    {
        int pt  = threadIdx.x >> 3;
        int sub = threadIdx.x & 7;
        int i0 = si[pt * 3], i1 = si[pt * 3 + 1], i2 = si[pt * 3 + 2];
        float w0 = sw[pt * 3], w1 = sw[pt * 3 + 1], w2 = sw[pt * 3 + 2];
        const bf16_t* P2 = P2b + (size_t)bb * N2 * C2;
        const bf16_t* r0 = P2 + (size_t)i0 * C2;
        const bf16_t* r1 = P2 + (size_t)i1 * C2;
        const bf16_t* r2 = P2 + (size_t)i2 * C2;
        bf16_t* Ar = As + pt * ASTRIDE;
#pragma unroll
        for (int q = 0; q < 4; ++q) {
            int c = q * 64 + sub * 8;
            bf16x8 va = *(const bf16x8*)(r0 + c);
            bf16x8 vb = *(const bf16x8*)(r1 + c);
            bf16x8 vc = *(const bf16x8*)(r2 + c);
            bf16x8 o;
#pragma unroll
            for (int j = 0; j < 8; ++j)
                o[j] = (bf16_t)(w0 * (float)va[j] + w1 * (float)vb[j] + w2 * (float)vc[j]);
            *(bf16x8*)(Ar + c) = o;
        }
        const float* p1 = points1 + (size_t)(row0 + pt) * C1;
#pragma unroll
        for (int q = 0; q < 4; ++q) {
            int c = q * 32 + sub * 4;
            float4 v = *(const float4*)(p1 + c);
            bf16x4 o;
            o[0] = (bf16_t)v.x; o[1] = (bf16_t)v.y; o[2] = (bf16_t)v.z; o[3] = (bf16_t)v.w;
            *(bf16x4*)(Ar + C2 + c) = o;
        }
    }
    __syncthreads();
    // ---- phase 2: wave w -> cols [w*32, w*32+32), all 64 rows. W slice private to wave. ----
    int w    = threadIdx.x >> 6;
    int lane = threadIdx.x & 63;
    int l15  = lane & 15;
    int quad = lane >> 4;
    f32x4 acc[4][2] = {};
    const bf16_t* Wp = Wt + ((size_t)(w * 32) + l15) * CIN + quad * 8;
    const bf16_t* Al = As + l15 * ASTRIDE + quad * 8;
    for (int k0 = 0; k0 < CIN; k0 += 32) {
        bf16x8 bfr[2];
#pragma unroll
        for (int ni = 0; ni < 2; ++ni) bfr[ni] = *(const bf16x8*)(Wp + (size_t)ni * 16 * CIN + k0);
#pragma unroll
        for (int mi = 0; mi < 4; ++mi) {
            bf16x8 a = *(const bf16x8*)(Al + mi * 16 * ASTRIDE + k0);
            acc[mi][0] = __builtin_amdgcn_mfma_f32_16x16x32_bf16(a, bfr[0], acc[mi][0], 0, 0, 0);
            acc[mi][1] = __builtin_amdgcn_mfma_f32_16x16x32_bf16(a, bfr[1], acc[mi][1], 0, 0, 0);
        }
    }
    // ---- per-block column stats first (reads acc only) ----
#pragma unroll
    for (int ni = 0; ni < 2; ++ni) {
        float s = 0.0f, ss = 0.0f;
#pragma unroll
        for (int mi = 0; mi < 4; ++mi)
#pragma unroll
            for (int r = 0; r < 4; ++r) {
                float v = acc[mi][ni][r];
                s += v; ss = fmaf(v, v, ss);
            }
        s  += __shfl_xor(s, 16);  s  += __shfl_xor(s, 32);
        ss += __shfl_xor(ss, 16); ss += __shfl_xor(ss, 32);
        if (quad == 0) {
            int cl = w * 32 + ni * 16 + l15;      // unique per lane across block
            float* slot = P0 + (size_t)blockIdx.x * 512;
            slot[cl]       = s;
            slot[256 + cl] = ss;
        }
    }
    // ---- epilogue: stage C in LDS (As reuse; all k-loop reads done), coalesced store ----
    __syncthreads();
#pragma unroll
    for (int mi = 0; mi < 4; ++mi)
#pragma unroll
        for (int ni = 0; ni < 2; ++ni) {
            int col = w * 32 + ni * 16 + l15;
            int rw  = mi * 16 + quad * 4;
#pragma unroll
            for (int r = 0; r < 4; ++r)
                As[(rw + r) * CSTRIDE + col] = (bf16_t)acc[mi][ni][r];
        }
    __syncthreads();
#pragma unroll
    for (int rI = 0; rI < 4; ++rI) {
        int idx = rI * 512 + threadIdx.x;     // 0..2047
        int row = idx >> 5;
        int c8  = (idx & 31) * 8;
        *(bf16x8*)(H + (size_t)(row0 + row) * 256 + c8) = *(const bf16x8*)(As + row * CSTRIDE + c8);
    }
}

// ---------------- GEMM2: A staged in LDS with fused BN+ReLU (1x), 8 col-waves (W 1x) ----------
// grid NP/64 = 1024 blocks. Same coalesced LDS-staged epilogue as gemm1.
__global__ __launch_bounds__(512) void gemm2_kernel(const bf16_t* __restrict__ A,
                                                    const bf16_t* __restrict__ Wt,
                                                    const float* __restrict__ scale,
                                                    const float* __restrict__ shift,
                                                    bf16_t* __restrict__ H,
                                                    float* __restrict__ P1) {
    const int K = M0;   // 256
    __shared__ bf16_t As2[64 * A2STRIDE];   // 33792 B
    __shared__ float ssc[256], ssh[256];    // 2 KB
    int row0 = blockIdx.x * 64;
    if (threadIdx.x < 256) { ssc[threadIdx.x] = scale[threadIdx.x]; ssh[threadIdx.x] = shift[threadIdx.x]; }
    __syncthreads();
    // stage A-tile: 64 rows x 256 ch, BN+ReLU applied once; coalesced 16B loads
#pragma unroll
    for (int rI = 0; rI < 4; ++rI) {
        int idx = rI * 512 + threadIdx.x;     // 0..2047
        int row = idx >> 5;
        int c8  = (idx & 31) * 8;
        bf16x8 raw = *(const bf16x8*)(A + (size_t)(row0 + row) * 256 + c8);
        bf16x8 t;
#pragma unroll
        for (int j = 0; j < 8; ++j)
            t[j] = (bf16_t)fmaxf(fmaf((float)raw[j], ssc[c8 + j], ssh[c8 + j]), 0.0f);
        *(bf16x8*)(As2 + row * A2STRIDE + c8) = t;
    }
    __syncthreads();
    int w    = threadIdx.x >> 6;
    int lane = threadIdx.x & 63;
    int l15  = lane & 15;
    int quad = lane >> 4;
    f32x4 acc[4][2] = {};
    const bf16_t* Wp = Wt + ((size_t)(w * 32) + l15) * K + quad * 8;
    const bf16_t* Al = As2 + l15 * A2STRIDE + quad * 8;
    for (int k0 = 0; k0 < K; k0 += 32) {
        bf16x8 bfr[2];
#pragma unroll
        for (int ni = 0; ni < 2; ++ni) bfr[ni] = *(const bf16x8*)(Wp + (size_t)ni * 16 * K + k0);
#pragma unroll
        for (int mi = 0; mi < 4; ++mi) {
            bf16x8 a = *(const bf16x8*)(Al + mi * 16 * A2STRIDE + k0);
            acc[mi][0] = __builtin_amdgcn_mfma_f32_16x16x32_bf16(a, bfr[0], acc[mi][0], 0, 0, 0);
            acc[mi][1] = __builtin_amdgcn_mfma_f32_16x16x32_bf16(a, bfr[1], acc[mi][1], 0, 0, 0);
        }
    }
    // ---- per-block column stats first (reads acc only) ----
#pragma unroll
    for (int ni = 0; ni < 2; ++ni) {
        float s = 0.0f, ss = 0.0f;
#pragma unroll
        for (int mi = 0; mi < 4; ++mi)
#pragma unroll
            for (int r = 0; r < 4; ++r) {
                float v = acc[mi][ni][r];
                s += v; ss = fmaf(v, v, ss);
            }
        s  += __shfl_xor(s, 16);  s  += __shfl_xor(s, 32);
        ss += __shfl_xor(ss, 16); ss += __shfl_xor(ss, 32);
        if (quad == 0) {
            int cl = w * 32 + ni * 16 + l15;
            float* slot = P1 + (size_t)blockIdx.x * 512;
            slot[cl]       = s;
            slot[256 + cl] = ss;
        }
    }
    // ---- epilogue: stage C in LDS (As2 reuse; all k-loop reads done), coalesced store ----
    __syncthreads();
#pragma unroll
    for (int mi = 0; mi < 4; ++mi)
#pragma unroll
        for (int ni = 0; ni < 2; ++ni) {
            int col = w * 32 + ni * 16 + l15;
            int rw  = mi * 16 + quad * 4;
#pragma unroll
            for (int r = 0; r < 4; ++r)
                As2[(rw + r) * CSTRIDE + col] = (bf16_t)acc[mi][ni][r];
        }
    __syncthreads();
#pragma unroll
    for (int rI = 0; rI < 4; ++rI) {
        int idx = rI * 512 + threadIdx.x;     // 0..2047
        int row = idx >> 5;
        int c8  = (idx & 31) * 8;
        *(bf16x8*)(H + (size_t)(row0 + row) * 256 + c8) = *(const bf16x8*)(As2 + row * CSTRIDE + c8);
    }
}

// ---------------- reduce per-block partials -> scale/shift (one block per channel) ----------------
__global__ __launch_bounds__(256) void finalize_partials_kernel(const float* __restrict__ P, int nblk,
                                                                const float* __restrict__ gamma,
                                                                const float* __restrict__ beta,
                                                                float* __restrict__ scale,
                                                                float* __restrict__ shift) {
    int c = blockIdx.x;
    float s = 0.0f, ss = 0.0f;
    for (int bb = threadIdx.x; bb < nblk; bb += 256) {
        const float* row = P + (size_t)bb * 512;
        s  += row[c];
        ss += row[256 + c];
    }
#pragma unroll
    for (int k = 32; k >= 1; k >>= 1) { s += __shfl_xor(s, k); ss += __shfl_xor(ss, k); }
    __shared__ float as_[4], ass_[4];
    int w = threadIdx.x >> 6;
    if ((threadIdx.x & 63) == 0) { as_[w] = s; ass_[w] = ss; }
    __syncthreads();
    if (threadIdx.x == 0) {
        float S  = as_[0] + as_[1] + as_[2] + as_[3];
        float SS = ass_[0] + ass_[1] + ass_[2] + ass_[3];
        float m   = S * (1.0f / NP);
        float var = SS * (1.0f / NP) - m * m;
        float sc  = rsqrtf(var + 1e-5f) * gamma[c];
        scale[c] = sc;
        shift[c] = fmaf(-m, sc, beta[c]);
    }
}

// ---------------- final BN+ReLU: H1 bf16 -> fp32 d_out ----------------
__global__ void bnrelu_final_kernel(const bf16_t* __restrict__ H, const float* __restrict__ scale,
                                    const float* __restrict__ shift, float* __restrict__ out) {
    int tid = blockIdx.x * 256 + threadIdx.x;
    bf16x8 v = *(const bf16x8*)(H + (size_t)tid * 8);
    int c = (tid & 31) * 8;
    float4 o0, o1;
    o0.x = fmaxf(fmaf((float)v[0], scale[c + 0], shift[c + 0]), 0.0f);
    o0.y = fmaxf(fmaf((float)v[1], scale[c + 1], shift[c + 1]), 0.0f);
    o0.z = fmaxf(fmaf((float)v[2], scale[c + 2], shift[c + 2]), 0.0f);
    o0.w = fmaxf(fmaf((float)v[3], scale[c + 3], shift[c + 3]), 0.0f);
    o1.x = fmaxf(fmaf((float)v[4], scale[c + 4], shift[c + 4]), 0.0f);
    o1.y = fmaxf(fmaf((float)v[5], scale[c + 5], shift[c + 5]), 0.0f);
    o1.z = fmaxf(fmaf((float)v[6], scale[c + 6], shift[c + 6]), 0.0f);
    o1.w = fmaxf(fmaf((float)v[7], scale[c + 7], shift[c + 7]), 0.0f);
    ((float4*)out)[tid * 2]     = o0;
    ((float4*)out)[tid * 2 + 1] = o1;
}

extern "C" void kernel_launch(void* const* d_in, const int* in_sizes, int n_in,
                              void* d_out, int out_size, void* d_ws, size_t ws_size,
                              hipStream_t stream) {
    const float* xyz1    = (const float*)d_in[0];
    const float* xyz2    = (const float*)d_in[1];
    const float* points1 = (const float*)d_in[2];
    const float* points2 = (const float*)d_in[3];
    const float* W0      = (const float*)d_in[4];
    const float* g0      = (const float*)d_in[5];
    const float* b0      = (const float*)d_in[6];
    const float* W1      = (const float*)d_in[7];
    const float* g1      = (const float*)d_in[8];
    const float* b1      = (const float*)d_in[9];
    float* out = (float*)d_out;

    // ws layout (float offsets), 81.6 MB total (P2b de-aliased from pd: front kernel
    // runs cvt concurrent with nn3). H0 aliases dead pd/pi (merge precedes gemm1).
    float* wsf    = (float*)d_ws;
    float* scale0 = wsf + 0;
    float* shift0 = wsf + 256;
    float* scale1 = wsf + 512;
    float* shift1 = wsf + 768;
    float* w3     = wsf + 2048;                       // 196608 f -> 198656
    int*   idx3   = (int*)(wsf + 198656);             // 196608 i -> 395264
    bf16_t* Wb0   = (bf16_t*)(wsf + 395264);          // 98304 bf16 -> 444416
    bf16_t* Wb1   = (bf16_t*)(wsf + 444416);          // 65536 bf16 -> 477184
    bf16_t* P2b   = (bf16_t*)(wsf + 477184);          // 4194304 bf16 -> 2574336
    float* pd     = wsf + 2574336;                    // NP*24 f -> 4147200 (dead after merge)
    int*   pi     = (int*)(wsf + 4147200);            // NP*24 i -> 5720064 (dead after merge)
    bf16_t* H0    = (bf16_t*)(wsf + 2574336);         // NP*256 bf16 -> 10962944, aliases pd/pi
    bf16_t* H1    = (bf16_t*)(wsf + 10962944);        // NP*256 bf16 -> 19351552
    float* P0     = wsf + 19351552;                   // 1024*512 f -> 19875840
    float* P1     = wsf + 19875840;                   // 1024*512 f -> 20400128

    // fused front end: nn3 partials + points2->bf16 + W->bf16 (one dispatch)
    front_kernel<<<NN3_BLKS + P2B_BLKS + W_BLKS, 256, 0, stream>>>(
        xyz1, xyz2, points2, W0, W1, P2b, Wb0, Wb1, pd, pi);
    nn3_merge_kernel<<<NP / 256, 256, 0, stream>>>(pd, pi, idx3, w3);

    // layer 0
    gemm1_fused_kernel<<<NP / 64, 512, 0, stream>>>(points1, P2b, idx3, w3, Wb0, H0, P0);
    finalize_partials_kernel<<<256, 256, 0, stream>>>(P0, NP / 64, g0, b0, scale0, shift0);

    // layer 1
    gemm2_kernel<<<NP / 64, 512, 0, stream>>>(H0, Wb1, scale0, shift0, H1, P1);
    finalize_partials_kernel<<<256, 256, 0, stream>>>(P1, NP / 64, g1, b1, scale1, shift1);

    // final BN+ReLU -> fp32 output
    bnrelu_final_kernel<<<NP * 256 / 8 / 256, 256, 0, stream>>>(H1, scale1, shift1, out);
}